// Round 1
// baseline (3209.905 us; speedup 1.0000x reference)
//
#include <hip/hip_runtime.h>
#include <hip/hip_bf16.h>
#include <math.h>

#define T_SEQ 1024
#define HIDN  2048
#define NH    64
#define NKV   4
#define DH    64
#define GQ    16
#define BSZ   64
#define NBLK  16
#define SSEL  8
#define WWIN  512
#define SCL   0.125f
#define NEGF  -1e30f

// ---------------- fp32 tiled GEMM: C[M,N] = A[M,K] @ B[K,N] ----------------
// Requires M%64==0, N%64==0, K%16==0 (true for all our shapes).
__global__ __launch_bounds__(256) void gemm_f32(const float* __restrict__ A,
                                                const float* __restrict__ B,
                                                float* __restrict__ C,
                                                int M, int N, int K) {
  __shared__ float As[16][65];
  __shared__ float Bs[16][64];
  int tid = threadIdx.x;
  int tx = tid & 15, ty = tid >> 4;
  int row0 = blockIdx.y * 64, col0 = blockIdx.x * 64;
  float acc[4][4] = {};
  for (int k0 = 0; k0 < K; k0 += 16) {
#pragma unroll
    for (int l = 0; l < 4; ++l) {
      int i = tid + l * 256;
      As[i & 15][i >> 4] = A[(size_t)(row0 + (i >> 4)) * K + k0 + (i & 15)];
    }
#pragma unroll
    for (int l = 0; l < 4; ++l) {
      int i = tid + l * 256;
      Bs[i >> 6][i & 63] = B[(size_t)(k0 + (i >> 6)) * N + col0 + (i & 63)];
    }
    __syncthreads();
#pragma unroll
    for (int kk = 0; kk < 16; ++kk) {
      float a[4], b[4];
#pragma unroll
      for (int i = 0; i < 4; ++i) a[i] = As[kk][ty * 4 + i];
#pragma unroll
      for (int j = 0; j < 4; ++j) b[j] = Bs[kk][tx * 4 + j];
#pragma unroll
      for (int i = 0; i < 4; ++i)
#pragma unroll
        for (int j = 0; j < 4; ++j) acc[i][j] = fmaf(a[i], b[j], acc[i][j]);
    }
    __syncthreads();
  }
#pragma unroll
  for (int i = 0; i < 4; ++i)
#pragma unroll
    for (int j = 0; j < 4; ++j)
      C[(size_t)(row0 + ty * 4 + i) * N + col0 + tx * 4 + j] = acc[i][j];
}

// ---------------- RoPE in place: x is [T][nheads][64] ----------------
__global__ void rope_f32(float* __restrict__ x, int nheads) {
  int idx = blockIdx.x * blockDim.x + threadIdx.x;
  int total = T_SEQ * nheads * 32;
  if (idx >= total) return;
  int i = idx & 31;
  int h = (idx >> 5) % nheads;
  int t = idx / (32 * nheads);
  float inv = powf(10000.0f, -(float)i / 32.0f);
  float f = (float)t * inv;
  float c = cosf(f), s = sinf(f);
  float* p = x + ((size_t)t * nheads + h) * DH;
  float x1 = p[i], x2 = p[i + 32];
  p[i]      = x1 * c - x2 * s;
  p[i + 32] = x1 * s + x2 * c;
}

// ---------------- block means for compressed attention ----------------
__global__ void cmp_mean(const float* __restrict__ k, const float* __restrict__ v,
                         float* __restrict__ kc, float* __restrict__ vc) {
  int idx = blockIdx.x * blockDim.x + threadIdx.x;  // n*256 + hkv*64 + d
  if (idx >= NBLK * NKV * DH) return;
  int d = idx & 63, hkv = (idx >> 6) & 3, n = idx >> 8;
  float sk = 0.f, sv = 0.f;
  for (int j = 0; j < BSZ; ++j) {
    size_t off = ((size_t)(n * BSZ + j) * NKV + hkv) * DH + d;
    sk += k[off];
    sv += v[off];
  }
  kc[idx] = sk * (1.0f / 64.0f);
  vc[idx] = sv * (1.0f / 64.0f);
}

__device__ __forceinline__ float wred_sum(float x) {
#pragma unroll
  for (int m = 1; m < 64; m <<= 1) x += __shfl_xor(x, m, 64);
  return x;
}
__device__ __forceinline__ float wred_max(float x) {
#pragma unroll
  for (int m = 1; m < 64; m <<= 1) x = fmaxf(x, __shfl_xor(x, m, 64));
  return x;
}

// ---------------- compressed attention + importance ----------------
// one wave per (t, h); lane = d
__global__ __launch_bounds__(64) void cmp_attn(const float* __restrict__ q,
                                               const float* __restrict__ kc,
                                               const float* __restrict__ vc,
                                               float* __restrict__ ocmp,
                                               float* __restrict__ imp) {
  int h = blockIdx.x & 63;
  int t = blockIdx.x >> 6;
  int lane = threadIdx.x;
  int hkv = h >> 4;
  size_t qoff = ((size_t)t * NH + h) * DH + lane;
  float qd = q[qoff];
  // block n valid iff n*64+63 <= t
  int nv = (t >= 63) ? (((t - 63) >> 6) + 1) : 0;
  if (nv == 0) { ocmp[qoff] = 0.f; return; }
  float s[NBLK];
#pragma unroll
  for (int n = 0; n < NBLK; ++n) {
    float part = (n < nv) ? qd * kc[n * (NKV * DH) + hkv * DH + lane] : 0.f;
    part = wred_sum(part);
    s[n] = part * SCL;
  }
  float m = -INFINITY;
#pragma unroll
  for (int n = 0; n < NBLK; ++n)
    if (n < nv) m = fmaxf(m, s[n]);
  float p[NBLK];
  float denom = 0.f;
#pragma unroll
  for (int n = 0; n < NBLK; ++n) {
    p[n] = (n < nv) ? expf(s[n] - m) : 0.f;
    denom += p[n];
  }
  float rd = 1.0f / denom;
  float od = 0.f;
#pragma unroll
  for (int n = 0; n < NBLK; ++n)
    od = fmaf(p[n] * rd, vc[n * (NKV * DH) + hkv * DH + lane], od);
  ocmp[qoff] = od;
  if (lane < nv) atomicAdd(&imp[((size_t)t * NKV + hkv) * NBLK + lane], p[lane] * rd);
}

// ---------------- top-8 block selection per (t, hkv) ----------------
__global__ void topk_kernel(const float* __restrict__ imp, int* __restrict__ tidx) {
  int idx = blockIdx.x * blockDim.x + threadIdx.x;  // t*4 + hkv
  if (idx >= T_SEQ * NKV) return;
  int t = idx >> 2;
  int cur = t >> 6;
  float vals[NBLK];
#pragma unroll
  for (int n = 0; n < NBLK; ++n) {
    float v0;
    if (n > cur) v0 = -INFINITY;             // invalid (future)
    else if (n == 0 || n == cur) v0 = INFINITY;  // forced
    else v0 = imp[(size_t)idx * NBLK + n];
    vals[n] = v0;
  }
  for (int s = 0; s < SSEL; ++s) {
    float best = -INFINITY;
    int bi = -1;
#pragma unroll
    for (int n = 0; n < NBLK; ++n) {
      if (vals[n] > best) { best = vals[n]; bi = n; }  // strict > : lowest index wins ties (matches lax.top_k)
    }
    if (bi >= 0) vals[bi] = -INFINITY;
    tidx[(size_t)idx * SSEL + s] = bi;  // -1 => slot invalid
  }
}

// ---------------- selection + SWA attention + gated combine ----------------
// one wave per (t, h). oattn may alias q (each block reads/writes only its own row).
__global__ __launch_bounds__(64) void slc_swa_attn(
    const float* __restrict__ q, const float* __restrict__ k,
    const float* __restrict__ v, const float* __restrict__ ocmp,
    const float* __restrict__ graw, const int* __restrict__ tidx,
    float* __restrict__ oattn) {
  __shared__ float qs[DH];
  __shared__ float ps[SSEL * BSZ];
  int h = blockIdx.x & 63;
  int t = blockIdx.x >> 6;
  int lane = threadIdx.x;
  int hkv = h >> 4;
  size_t qoff = ((size_t)t * NH + h) * DH;
  qs[lane] = q[qoff + lane];
  __syncthreads();

  // ======== selection attention ========
  int bsel[SSEL];
#pragma unroll
  for (int s = 0; s < SSEL; ++s) bsel[s] = tidx[((size_t)t * NKV + hkv) * SSEL + s];
  float sc[SSEL];
#pragma unroll
  for (int s = 0; s < SSEL; ++s) {
    int b = bsel[s];
    float val = NEGF;
    if (b >= 0) {
      int pos = b * BSZ + lane;
      if (pos <= t) {
        const float* kp = k + ((size_t)pos * NKV + hkv) * DH;
        float acc = 0.f;
#pragma unroll
        for (int d = 0; d < DH; ++d) acc = fmaf(qs[d], kp[d], acc);
        val = acc * SCL;
      }
    }
    sc[s] = val;
  }
  float m = sc[0];
#pragma unroll
  for (int s = 1; s < SSEL; ++s) m = fmaxf(m, sc[s]);
  m = wred_max(m);
  float lsum = 0.f;
#pragma unroll
  for (int s = 0; s < SSEL; ++s) {
    sc[s] = expf(sc[s] - m);   // masked entries: expf(-1e30) == 0, same as jax
    lsum += sc[s];
  }
  float rd = 1.0f / wred_sum(lsum);
#pragma unroll
  for (int s = 0; s < SSEL; ++s) ps[s * BSZ + lane] = sc[s] * rd;
  __syncthreads();
  float o_slc = 0.f;
#pragma unroll
  for (int s = 0; s < SSEL; ++s) {
    int b = bsel[s];
    if (b < 0) continue;
    const float* vp = v + ((size_t)(b * BSZ) * NKV + hkv) * DH + lane;
    int jmax = min(BSZ, t - b * BSZ + 1);   // only pos<=t contribute (ps==0 beyond)
    for (int j = 0; j < jmax; ++j)
      o_slc = fmaf(ps[s * BSZ + j], vp[(size_t)j * (NKV * DH)], o_slc);
  }
  __syncthreads();

  // ======== sliding-window attention: keys in [t-511, t] ========
  int base = t - (WWIN - 1);
#pragma unroll
  for (int c = 0; c < 8; ++c) {
    int pos = base + c * BSZ + lane;
    float val = NEGF;
    if (pos >= 0) {  // pos <= t guaranteed
      const float* kp = k + ((size_t)pos * NKV + hkv) * DH;
      float acc = 0.f;
#pragma unroll
      for (int d = 0; d < DH; ++d) acc = fmaf(qs[d], kp[d], acc);
      val = acc * SCL;
    }
    sc[c] = val;
  }
  m = sc[0];
#pragma unroll
  for (int c = 1; c < 8; ++c) m = fmaxf(m, sc[c]);
  m = wred_max(m);
  lsum = 0.f;
#pragma unroll
  for (int c = 0; c < 8; ++c) {
    sc[c] = expf(sc[c] - m);
    lsum += sc[c];
  }
  rd = 1.0f / wred_sum(lsum);
#pragma unroll
  for (int c = 0; c < 8; ++c) ps[c * BSZ + lane] = sc[c] * rd;
  __syncthreads();
  float o_swa = 0.f;
#pragma unroll
  for (int c = 0; c < 8; ++c) {
    int pos0 = base + c * BSZ;
    int jstart = pos0 < 0 ? -pos0 : 0;
    for (int j = jstart; j < BSZ; ++j) {
      int pos = pos0 + j;
      o_swa = fmaf(ps[c * BSZ + j], v[((size_t)pos * NKV + hkv) * DH + lane], o_swa);
    }
  }

  // ======== gated combine ========
  size_t goff = ((size_t)t * NH + h) * 3;
  float g0 = 1.f / (1.f + expf(-graw[goff + 0]));
  float g1 = 1.f / (1.f + expf(-graw[goff + 1]));
  float g2 = 1.f / (1.f + expf(-graw[goff + 2]));
  float oc = ocmp[qoff + lane];
  oattn[qoff + lane] = g0 * oc + g1 * o_slc + g2 * o_swa;
}

extern "C" void kernel_launch(void* const* d_in, const int* in_sizes, int n_in,
                              void* d_out, int out_size, void* d_ws, size_t ws_size,
                              hipStream_t stream) {
  const float* x  = (const float*)d_in[0];
  const float* Wq = (const float*)d_in[1];
  const float* Wk = (const float*)d_in[2];
  const float* Wv = (const float*)d_in[3];
  const float* Wg = (const float*)d_in[4];
  const float* Wo = (const float*)d_in[5];
  float* out = (float*)d_out;

  float* ws = (float*)d_ws;
  float* qbuf = ws;                      // T*NH*DH   = 4,194,304  (later reused as o_attn)
  float* kbuf = qbuf + 4194304;          // T*NKV*DH  = 262,144
  float* vbuf = kbuf + 262144;           // 262,144
  float* gbuf = vbuf + 262144;           // T*NH*3    = 196,608
  float* ocmp = gbuf + 196608;           // 4,194,304
  float* kc   = ocmp + 4194304;          // 4,096
  float* vc   = kc + 4096;               // 4,096
  float* impb = vc + 4096;               // T*NKV*NBLK = 65,536
  int*   tidx = (int*)(impb + 65536);    // T*NKV*SSEL = 32,768 ints
  // total ~35.2 MiB

  // imp is accumulated with atomics -> zero it every call (ws is re-poisoned)
  hipMemsetAsync(impb, 0, 65536 * sizeof(float), stream);

  // projections
  gemm_f32<<<dim3(4096 / 64, 1024 / 64), 256, 0, stream>>>(x, Wq, qbuf, 1024, 4096, 2048);
  gemm_f32<<<dim3(256 / 64, 16), 256, 0, stream>>>(x, Wk, kbuf, 1024, 256, 2048);
  gemm_f32<<<dim3(256 / 64, 16), 256, 0, stream>>>(x, Wv, vbuf, 1024, 256, 2048);
  gemm_f32<<<dim3(192 / 64, 16), 256, 0, stream>>>(x, Wg, gbuf, 1024, 192, 2048);

  // rope on q and k
  rope_f32<<<(T_SEQ * NH * 32 + 255) / 256, 256, 0, stream>>>(qbuf, NH);
  rope_f32<<<(T_SEQ * NKV * 32 + 255) / 256, 256, 0, stream>>>(kbuf, NKV);

  // compressed means
  cmp_mean<<<(NBLK * NKV * DH + 255) / 256, 256, 0, stream>>>(kbuf, vbuf, kc, vc);

  // compressed attention + importance
  cmp_attn<<<T_SEQ * NH, 64, 0, stream>>>(qbuf, kc, vc, ocmp, impb);

  // top-k selection
  topk_kernel<<<(T_SEQ * NKV + 255) / 256, 256, 0, stream>>>(impb, tidx);

  // selection + swa + combine (writes o_attn in place over qbuf)
  slc_swa_attn<<<T_SEQ * NH, 64, 0, stream>>>(qbuf, kbuf, vbuf, ocmp, gbuf, tidx, qbuf);

  // output projection
  gemm_f32<<<dim3(2048 / 64, 1024 / 64), 256, 0, stream>>>(qbuf, Wo, out, 1024, 2048, 4096);
}

// Round 2
// 1828.464 us; speedup vs baseline: 1.7555x; 1.7555x over previous
//
#include <hip/hip_runtime.h>
#include <hip/hip_bf16.h>
#include <math.h>

#define T_SEQ 1024
#define HIDN  2048
#define NH    64
#define NKV   4
#define DH    64
#define GQ    16
#define BSZ   64
#define NBLK  16
#define SSEL  8
#define WWIN  512
#define SCL   0.125f
#define NEGF  -1e30f

#define SB_RL 516   // Sb row length (512 keys + pad)
#define QT_RL 16    // qt row length

// ---------------- fp32 tiled GEMM: C[M,N] = A[M,K] @ B[K,N] ----------------
__global__ __launch_bounds__(256) void gemm_f32(const float* __restrict__ A,
                                                const float* __restrict__ B,
                                                float* __restrict__ C,
                                                int M, int N, int K) {
  __shared__ float As[16][65];
  __shared__ float Bs[16][64];
  int tid = threadIdx.x;
  int tx = tid & 15, ty = tid >> 4;
  int row0 = blockIdx.y * 64, col0 = blockIdx.x * 64;
  float acc[4][4] = {};
  for (int k0 = 0; k0 < K; k0 += 16) {
#pragma unroll
    for (int l = 0; l < 4; ++l) {
      int i = tid + l * 256;
      As[i & 15][i >> 4] = A[(size_t)(row0 + (i >> 4)) * K + k0 + (i & 15)];
    }
#pragma unroll
    for (int l = 0; l < 4; ++l) {
      int i = tid + l * 256;
      Bs[i >> 6][i & 63] = B[(size_t)(k0 + (i >> 6)) * N + col0 + (i & 63)];
    }
    __syncthreads();
#pragma unroll
    for (int kk = 0; kk < 16; ++kk) {
      float a[4], b[4];
#pragma unroll
      for (int i = 0; i < 4; ++i) a[i] = As[kk][ty * 4 + i];
#pragma unroll
      for (int j = 0; j < 4; ++j) b[j] = Bs[kk][tx * 4 + j];
#pragma unroll
      for (int i = 0; i < 4; ++i)
#pragma unroll
        for (int j = 0; j < 4; ++j) acc[i][j] = fmaf(a[i], b[j], acc[i][j]);
    }
    __syncthreads();
  }
#pragma unroll
  for (int i = 0; i < 4; ++i)
#pragma unroll
    for (int j = 0; j < 4; ++j)
      C[(size_t)(row0 + ty * 4 + i) * N + col0 + tx * 4 + j] = acc[i][j];
}

// ---------------- RoPE in place: x is [T][nheads][64] ----------------
__global__ void rope_f32(float* __restrict__ x, int nheads) {
  int idx = blockIdx.x * blockDim.x + threadIdx.x;
  int total = T_SEQ * nheads * 32;
  if (idx >= total) return;
  int i = idx & 31;
  int h = (idx >> 5) % nheads;
  int t = idx / (32 * nheads);
  float inv = powf(10000.0f, -(float)i / 32.0f);
  float f = (float)t * inv;
  float c = cosf(f), s = sinf(f);
  float* p = x + ((size_t)t * nheads + h) * DH;
  float x1 = p[i], x2 = p[i + 32];
  p[i]      = x1 * c - x2 * s;
  p[i + 32] = x1 * s + x2 * c;
}

// ---------------- block means for compressed attention ----------------
__global__ void cmp_mean(const float* __restrict__ k, const float* __restrict__ v,
                         float* __restrict__ kc, float* __restrict__ vc) {
  int idx = blockIdx.x * blockDim.x + threadIdx.x;  // n*256 + hkv*64 + d
  if (idx >= NBLK * NKV * DH) return;
  int d = idx & 63, hkv = (idx >> 6) & 3, n = idx >> 8;
  float sk = 0.f, sv = 0.f;
  for (int j = 0; j < BSZ; ++j) {
    size_t off = ((size_t)(n * BSZ + j) * NKV + hkv) * DH + d;
    sk += k[off];
    sv += v[off];
  }
  kc[idx] = sk * (1.0f / 64.0f);
  vc[idx] = sv * (1.0f / 64.0f);
}

__device__ __forceinline__ float wred_sum(float x) {
#pragma unroll
  for (int m = 1; m < 64; m <<= 1) x += __shfl_xor(x, m, 64);
  return x;
}

// ---------------- compressed attention + importance ----------------
__global__ __launch_bounds__(64) void cmp_attn(const float* __restrict__ q,
                                               const float* __restrict__ kc,
                                               const float* __restrict__ vc,
                                               float* __restrict__ ocmp,
                                               float* __restrict__ imp) {
  int h = blockIdx.x & 63;
  int t = blockIdx.x >> 6;
  int lane = threadIdx.x;
  int hkv = h >> 4;
  size_t qoff = ((size_t)t * NH + h) * DH + lane;
  float qd = q[qoff];
  int nv = (t >= 63) ? (((t - 63) >> 6) + 1) : 0;
  if (nv == 0) { ocmp[qoff] = 0.f; return; }
  float s[NBLK];
#pragma unroll
  for (int n = 0; n < NBLK; ++n) {
    float part = (n < nv) ? qd * kc[n * (NKV * DH) + hkv * DH + lane] : 0.f;
    part = wred_sum(part);
    s[n] = part * SCL;
  }
  float m = -INFINITY;
#pragma unroll
  for (int n = 0; n < NBLK; ++n)
    if (n < nv) m = fmaxf(m, s[n]);
  float p[NBLK];
  float denom = 0.f;
#pragma unroll
  for (int n = 0; n < NBLK; ++n) {
    p[n] = (n < nv) ? expf(s[n] - m) : 0.f;
    denom += p[n];
  }
  float rd = 1.0f / denom;
  float od = 0.f;
#pragma unroll
  for (int n = 0; n < NBLK; ++n)
    od = fmaf(p[n] * rd, vc[n * (NKV * DH) + hkv * DH + lane], od);
  ocmp[qoff] = od;
  if (lane < nv) atomicAdd(&imp[((size_t)t * NKV + hkv) * NBLK + lane], p[lane] * rd);
}

// ---------------- top-8 block selection per (t, hkv) ----------------
__global__ void topk_kernel(const float* __restrict__ imp, int* __restrict__ tidx) {
  int idx = blockIdx.x * blockDim.x + threadIdx.x;  // t*4 + hkv
  if (idx >= T_SEQ * NKV) return;
  int t = idx >> 2;
  int cur = t >> 6;
  float vals[NBLK];
#pragma unroll
  for (int n = 0; n < NBLK; ++n) {
    float v0;
    if (n > cur) v0 = -INFINITY;
    else if (n == 0 || n == cur) v0 = INFINITY;
    else v0 = imp[(size_t)idx * NBLK + n];
    vals[n] = v0;
  }
  for (int s = 0; s < SSEL; ++s) {
    float best = -INFINITY;
    int bi = -1;
#pragma unroll
    for (int n = 0; n < NBLK; ++n) {
      if (vals[n] > best) { best = vals[n]; bi = n; }
    }
    if (bi >= 0) vals[bi] = -INFINITY;
    tidx[(size_t)idx * SSEL + s] = bi;
  }
}

// ---------------- selection + SWA attention + gated combine (v2) ----------------
// One 256-thread block per (t, hkv); computes all 16 group heads.
// LDS: qt[64][16] (q transposed), KV[64*64] (Kt swizzled / Vs natural / partials),
//      Sb[16][516] (scores->probs). Total 53.5 KB -> 2-3 blocks/CU.
__global__ __launch_bounds__(256) void slc_swa_v2(
    const float* __restrict__ q, const float* __restrict__ k,
    const float* __restrict__ v, const float* __restrict__ ocmp,
    const float* __restrict__ graw, const int* __restrict__ tidx,
    float* __restrict__ oattn) {
  __shared__ __align__(16) float qt[64 * QT_RL];   // [d][h]
  __shared__ __align__(16) float KV[64 * 64];      // Kt / Vs / reduce scratch
  __shared__ __align__(16) float Sb[16 * SB_RL];   // [h][key]
  __shared__ int bselS[SSEL];

  int tid = threadIdx.x;
  int t   = blockIdx.x >> 2;
  int hkv = blockIdx.x & 3;
  int wv  = tid >> 6;          // wave id = d-chunk / j-chunk
  int lane = tid & 63;
  int hq  = lane >> 4;         // head quad 0..3
  int kq  = lane & 15;         // key/dim quad 0..15

  // ---- stage q (transposed) + selected block ids
  {
    const float* qrow = q + ((size_t)t * NH + hkv * GQ) * DH;
#pragma unroll
    for (int it = 0; it < 4; ++it) {
      int e = tid + it * 256;            // h = e>>6, d = e&63
      qt[(e & 63) * QT_RL + (e >> 6)] = qrow[e];
    }
    if (tid < SSEL) bselS[tid] = tidx[((size_t)t * NKV + hkv) * SSEL + tid];
  }
  __syncthreads();

  float o_slc[4][4] = {};
  float o_swa[4][4] = {};

  for (int half = 0; half < 2; ++half) {
    // ================= scores: 8 tiles of 64 keys =================
    for (int s = 0; s < SSEL; ++s) {
      int b = (half == 0) ? bselS[s] : 0;
      int pos0 = (half == 0) ? b * BSZ : (t - (WWIN - 1) + s * BSZ);
      bool active = (half == 1) || (b >= 0);

      if (active) {
        // stage Kt[d][j], additively swizzled in 4-float chunks
#pragma unroll
        for (int it = 0; it < 16; ++it) {
          int e = tid + it * 256;
          int j = e >> 6, dd = e & 63;
          int pos = pos0 + j;
          float val = 0.f;
          if (pos >= 0) val = k[((size_t)pos * NKV + hkv) * DH + dd];
          KV[dd * 64 + (((j >> 2) + dd) & 15) * 4 + (j & 3)] = val;
        }
      }
      __syncthreads();
      float acc[4][4] = {};
      if (active) {
        int dbase = wv * 16;
#pragma unroll
        for (int dd = 0; dd < 16; ++dd) {
          int d = dbase + dd;
          float4 k4 = *(const float4*)&KV[d * 64 + ((kq + d) & 15) * 4];
          float4 q4 = *(const float4*)&qt[d * QT_RL + hq * 4];
          acc[0][0] = fmaf(q4.x, k4.x, acc[0][0]); acc[0][1] = fmaf(q4.x, k4.y, acc[0][1]);
          acc[0][2] = fmaf(q4.x, k4.z, acc[0][2]); acc[0][3] = fmaf(q4.x, k4.w, acc[0][3]);
          acc[1][0] = fmaf(q4.y, k4.x, acc[1][0]); acc[1][1] = fmaf(q4.y, k4.y, acc[1][1]);
          acc[1][2] = fmaf(q4.y, k4.z, acc[1][2]); acc[1][3] = fmaf(q4.y, k4.w, acc[1][3]);
          acc[2][0] = fmaf(q4.z, k4.x, acc[2][0]); acc[2][1] = fmaf(q4.z, k4.y, acc[2][1]);
          acc[2][2] = fmaf(q4.z, k4.z, acc[2][2]); acc[2][3] = fmaf(q4.z, k4.w, acc[2][3]);
          acc[3][0] = fmaf(q4.w, k4.x, acc[3][0]); acc[3][1] = fmaf(q4.w, k4.y, acc[3][1]);
          acc[3][2] = fmaf(q4.w, k4.z, acc[3][2]); acc[3][3] = fmaf(q4.w, k4.w, acc[3][3]);
        }
      }
      __syncthreads();   // all Kt reads done; KV becomes partial buffer
      if (active) {
#pragma unroll
        for (int i = 0; i < 4; ++i) {
          float4 w4 = make_float4(acc[i][0], acc[i][1], acc[i][2], acc[i][3]);
          *(float4*)&KV[(wv * 16 + hq * 4 + i) * 64 + kq * 4] = w4;
        }
      }
      __syncthreads();
      {
        int h = tid >> 4, k4b = (tid & 15) * 4;
        float f[4] = {0.f, 0.f, 0.f, 0.f};
        if (active) {
#pragma unroll
          for (int w = 0; w < 4; ++w) {
            float4 p4 = *(const float4*)&KV[(w * 16 + h) * 64 + k4b];
            f[0] += p4.x; f[1] += p4.y; f[2] += p4.z; f[3] += p4.w;
          }
        }
        float out[4];
#pragma unroll
        for (int i = 0; i < 4; ++i) {
          int pos = pos0 + k4b + i;
          bool valid = active && (pos >= 0) && (pos <= t);
          out[i] = valid ? f[i] * SCL : NEGF;
        }
        *(float4*)&Sb[h * SB_RL + s * 64 + k4b] =
            make_float4(out[0], out[1], out[2], out[3]);
      }
      __syncthreads();
    }

    // ================= softmax over Sb rows [16][512] =================
    {
      int h = tid >> 4, seg = tid & 15;
      float4 r[8];
      float mx = -INFINITY;
#pragma unroll
      for (int c = 0; c < 8; ++c) {
        r[c] = *(const float4*)&Sb[h * SB_RL + seg * 4 + c * 64];
        mx = fmaxf(mx, fmaxf(fmaxf(r[c].x, r[c].y), fmaxf(r[c].z, r[c].w)));
      }
#pragma unroll
      for (int m = 1; m < 16; m <<= 1) mx = fmaxf(mx, __shfl_xor(mx, m, 64));
      float sum = 0.f;
#pragma unroll
      for (int c = 0; c < 8; ++c) {
        r[c].x = expf(r[c].x - mx); r[c].y = expf(r[c].y - mx);
        r[c].z = expf(r[c].z - mx); r[c].w = expf(r[c].w - mx);
        sum += r[c].x + r[c].y + r[c].z + r[c].w;
      }
#pragma unroll
      for (int m = 1; m < 16; m <<= 1) sum += __shfl_xor(sum, m, 64);
      float rd = 1.0f / sum;
#pragma unroll
      for (int c = 0; c < 8; ++c) {
        r[c].x *= rd; r[c].y *= rd; r[c].z *= rd; r[c].w *= rd;
        *(float4*)&Sb[h * SB_RL + seg * 4 + c * 64] = r[c];
      }
    }
    __syncthreads();

    // ================= PV: 8 tiles =================
    for (int s = 0; s < SSEL; ++s) {
      int b = (half == 0) ? bselS[s] : 0;
      int pos0 = (half == 0) ? b * BSZ : (t - (WWIN - 1) + s * BSZ);
      bool active = (half == 1) || (b >= 0);

      if (active) {
        // stage Vs[j][d] natural layout, float4
#pragma unroll
        for (int it = 0; it < 4; ++it) {
          int e = (tid + it * 256) * 4;
          int j = e >> 6, dd = e & 63;
          int pos = pos0 + j;
          float4 val = make_float4(0.f, 0.f, 0.f, 0.f);
          if (pos >= 0) val = *(const float4*)&v[((size_t)pos * NKV + hkv) * DH + dd];
          *(float4*)&KV[j * 64 + dd] = val;
        }
      }
      __syncthreads();
      if (active) {
        int jb = wv * 16;
        int dq = tid & 15;
        float tacc[4][4] = {};
#pragma unroll
        for (int jj = 0; jj < 16; jj += 4) {
          float4 p4[4], v4[4];
#pragma unroll
          for (int i = 0; i < 4; ++i)
            p4[i] = *(const float4*)&Sb[(hq * 4 + i) * SB_RL + s * 64 + jb + jj];
#pragma unroll
          for (int r = 0; r < 4; ++r)
            v4[r] = *(const float4*)&KV[(jb + jj + r) * 64 + dq * 4];
#pragma unroll
          for (int i = 0; i < 4; ++i) {
            tacc[i][0] = fmaf(p4[i].x, v4[0].x, tacc[i][0]);
            tacc[i][1] = fmaf(p4[i].x, v4[0].y, tacc[i][1]);
            tacc[i][2] = fmaf(p4[i].x, v4[0].z, tacc[i][2]);
            tacc[i][3] = fmaf(p4[i].x, v4[0].w, tacc[i][3]);
            tacc[i][0] = fmaf(p4[i].y, v4[1].x, tacc[i][0]);
            tacc[i][1] = fmaf(p4[i].y, v4[1].y, tacc[i][1]);
            tacc[i][2] = fmaf(p4[i].y, v4[1].z, tacc[i][2]);
            tacc[i][3] = fmaf(p4[i].y, v4[1].w, tacc[i][3]);
            tacc[i][0] = fmaf(p4[i].z, v4[2].x, tacc[i][0]);
            tacc[i][1] = fmaf(p4[i].z, v4[2].y, tacc[i][1]);
            tacc[i][2] = fmaf(p4[i].z, v4[2].z, tacc[i][2]);
            tacc[i][3] = fmaf(p4[i].z, v4[2].w, tacc[i][3]);
            tacc[i][0] = fmaf(p4[i].w, v4[3].x, tacc[i][0]);
            tacc[i][1] = fmaf(p4[i].w, v4[3].y, tacc[i][1]);
            tacc[i][2] = fmaf(p4[i].w, v4[3].z, tacc[i][2]);
            tacc[i][3] = fmaf(p4[i].w, v4[3].w, tacc[i][3]);
          }
        }
        if (half == 0) {
#pragma unroll
          for (int i = 0; i < 4; ++i)
#pragma unroll
            for (int c = 0; c < 4; ++c) o_slc[i][c] += tacc[i][c];
        } else {
#pragma unroll
          for (int i = 0; i < 4; ++i)
#pragma unroll
            for (int c = 0; c < 4; ++c) o_swa[i][c] += tacc[i][c];
        }
      }
      __syncthreads();
    }
  }

  // ================= cross-wave O reduction + gated combine =================
  int h = tid >> 4, d4 = (tid & 15) * 4;
  float4 oslc_f, oswa_f;
  {
#pragma unroll
    for (int i = 0; i < 4; ++i)
      *(float4*)&KV[(wv * 16 + hq * 4 + i) * 64 + (tid & 15) * 4] =
          make_float4(o_slc[i][0], o_slc[i][1], o_slc[i][2], o_slc[i][3]);
    __syncthreads();
    oslc_f = make_float4(0.f, 0.f, 0.f, 0.f);
#pragma unroll
    for (int w = 0; w < 4; ++w) {
      float4 p4 = *(const float4*)&KV[(w * 16 + h) * 64 + d4];
      oslc_f.x += p4.x; oslc_f.y += p4.y; oslc_f.z += p4.z; oslc_f.w += p4.w;
    }
    __syncthreads();
#pragma unroll
    for (int i = 0; i < 4; ++i)
      *(float4*)&KV[(wv * 16 + hq * 4 + i) * 64 + (tid & 15) * 4] =
          make_float4(o_swa[i][0], o_swa[i][1], o_swa[i][2], o_swa[i][3]);
    __syncthreads();
    oswa_f = make_float4(0.f, 0.f, 0.f, 0.f);
#pragma unroll
    for (int w = 0; w < 4; ++w) {
      float4 p4 = *(const float4*)&KV[(w * 16 + h) * 64 + d4];
      oswa_f.x += p4.x; oswa_f.y += p4.y; oswa_f.z += p4.z; oswa_f.w += p4.w;
    }
  }

  size_t go = ((size_t)t * NH + hkv * GQ + h) * 3;
  float g0 = 1.f / (1.f + expf(-graw[go + 0]));
  float g1 = 1.f / (1.f + expf(-graw[go + 1]));
  float g2 = 1.f / (1.f + expf(-graw[go + 2]));
  size_t oo = ((size_t)t * NH + hkv * GQ + h) * DH + d4;
  float4 oc = *(const float4*)&ocmp[oo];
  float4 res;
  res.x = g0 * oc.x + g1 * oslc_f.x + g2 * oswa_f.x;
  res.y = g0 * oc.y + g1 * oslc_f.y + g2 * oswa_f.y;
  res.z = g0 * oc.z + g1 * oslc_f.z + g2 * oswa_f.z;
  res.w = g0 * oc.w + g1 * oslc_f.w + g2 * oswa_f.w;
  *(float4*)&oattn[oo] = res;
}

extern "C" void kernel_launch(void* const* d_in, const int* in_sizes, int n_in,
                              void* d_out, int out_size, void* d_ws, size_t ws_size,
                              hipStream_t stream) {
  const float* x  = (const float*)d_in[0];
  const float* Wq = (const float*)d_in[1];
  const float* Wk = (const float*)d_in[2];
  const float* Wv = (const float*)d_in[3];
  const float* Wg = (const float*)d_in[4];
  const float* Wo = (const float*)d_in[5];
  float* out = (float*)d_out;

  float* ws = (float*)d_ws;
  float* qbuf = ws;                      // T*NH*DH (later o_attn in place)
  float* kbuf = qbuf + 4194304;          // T*NKV*DH
  float* vbuf = kbuf + 262144;
  float* gbuf = vbuf + 262144;           // T*NH*3
  float* ocmp = gbuf + 196608;
  float* kc   = ocmp + 4194304;
  float* vc   = kc + 4096;
  float* impb = vc + 4096;               // T*NKV*NBLK
  int*   tidx = (int*)(impb + 65536);    // T*NKV*SSEL

  hipMemsetAsync(impb, 0, 65536 * sizeof(float), stream);

  gemm_f32<<<dim3(4096 / 64, 1024 / 64), 256, 0, stream>>>(x, Wq, qbuf, 1024, 4096, 2048);
  gemm_f32<<<dim3(256 / 64, 16), 256, 0, stream>>>(x, Wk, kbuf, 1024, 256, 2048);
  gemm_f32<<<dim3(256 / 64, 16), 256, 0, stream>>>(x, Wv, vbuf, 1024, 256, 2048);
  gemm_f32<<<dim3(192 / 64, 16), 256, 0, stream>>>(x, Wg, gbuf, 1024, 192, 2048);

  rope_f32<<<(T_SEQ * NH * 32 + 255) / 256, 256, 0, stream>>>(qbuf, NH);
  rope_f32<<<(T_SEQ * NKV * 32 + 255) / 256, 256, 0, stream>>>(kbuf, NKV);

  cmp_mean<<<(NBLK * NKV * DH + 255) / 256, 256, 0, stream>>>(kbuf, vbuf, kc, vc);
  cmp_attn<<<T_SEQ * NH, 64, 0, stream>>>(qbuf, kc, vc, ocmp, impb);
  topk_kernel<<<(T_SEQ * NKV + 255) / 256, 256, 0, stream>>>(impb, tidx);

  slc_swa_v2<<<T_SEQ * NKV, 256, 0, stream>>>(qbuf, kbuf, vbuf, ocmp, gbuf, tidx, qbuf);

  gemm_f32<<<dim3(2048 / 64, 1024 / 64), 256, 0, stream>>>(qbuf, Wo, out, 1024, 2048, 4096);
}

// Round 5
// 950.121 us; speedup vs baseline: 3.3784x; 1.9245x over previous
//
// Round 4 resubmission. R3 failed because the harness compiled my prose; this
// response is a single cpp block only, with theory in comments.
//
// THEORY (unchanged from R2): move all projections to bf16 MFMA GEMMs
// (128x128x64 tile, global_load_lds 16B staging, fused k|v|g B^T), fix the
// Kt-staging LDS bank conflicts in slc_swa (lanes now span (d, j&3) so the
// b32 writes are conflict-free), and emit the attention output directly in
// bf16 to feed the Wo MFMA GEMM.
//
// PREDICTION: the two large GEMM dispatches ~500us -> ~40-60us each with
// MfmaUtil 20-35%; kvg GEMM ~15us; slc_swa 590 -> ~550us with
// SQ_LDS_BANK_CONFLICT 2.5e7 -> <5e6; total 1828 -> ~950-1050us; absmax
// rises to ~0.02-0.04 (bf16 inputs, fp32 accumulate), still under the
// 9.25e-2 threshold.

#include <hip/hip_runtime.h>
#include <hip/hip_bf16.h>
#include <math.h>

#define T_SEQ 1024
#define HIDN  2048
#define NH    64
#define NKV   4
#define DH    64
#define GQ    16
#define BSZ   64
#define NBLK  16
#define SSEL  8
#define WWIN  512
#define SCL   0.125f
#define NEGF  -1e30f

#define KVGS  768    // fused k|v|g row stride (k:0-255, v:256-511, g:512-703, pad:704-767)
#define SB_RL 516
#define QT_RL 16

typedef float  floatx4 __attribute__((ext_vector_type(4)));
typedef short  shortx8 __attribute__((ext_vector_type(8)));

__device__ __forceinline__ ushort f2bf(float f) {
  union { float f; unsigned u; } v; v.f = f;
  unsigned r = v.u + 0x7FFF + ((v.u >> 16) & 1);   // round-to-nearest-even
  return (ushort)(r >> 16);
}

__device__ __forceinline__ void gld_lds16(const ushort* g, ushort* l) {
  __builtin_amdgcn_global_load_lds((const __attribute__((address_space(1))) void*)g,
                                   (__attribute__((address_space(3))) void*)l, 16, 0, 0);
}

// ---------------- cast fp32 -> bf16 (elementwise, float4) ----------------
__global__ void cast_x(const float* __restrict__ in, ushort* __restrict__ out, int n4) {
  int i = blockIdx.x * blockDim.x + threadIdx.x;
  if (i >= n4) return;
  float4 f = ((const float4*)in)[i];
  ushort4 u;
  u.x = f2bf(f.x); u.y = f2bf(f.y); u.z = f2bf(f.z); u.w = f2bf(f.w);
  ((ushort4*)out)[i] = u;
}

// ---------------- cast+transpose: in fp32 [K][N] -> out bf16 [N][K] ----------------
__global__ __launch_bounds__(256) void cast_tr(const float* __restrict__ in,
                                               ushort* __restrict__ out, int K, int N) {
  __shared__ float tile[32][33];
  int k0 = blockIdx.y * 32, n0 = blockIdx.x * 32;
  int tx = threadIdx.x & 31, ty = threadIdx.x >> 5;  // ty 0..7
#pragma unroll
  for (int r = 0; r < 32; r += 8)
    tile[ty + r][tx] = in[(size_t)(k0 + ty + r) * N + n0 + tx];
  __syncthreads();
#pragma unroll
  for (int r = 0; r < 32; r += 8)
    out[(size_t)(n0 + ty + r) * K + k0 + tx] = f2bf(tile[tx][ty + r]);
}

// ---------------- bf16 MFMA GEMM: C[M][N] = A[M][K] @ Bt[N][K]^T ----------------
// BM=BN=128, BK=64; 256 threads = 4 waves in 2x2; global_load_lds 16B staging.
__global__ __launch_bounds__(256) void gemm_bf16(const ushort* __restrict__ A,
                                                 const ushort* __restrict__ Bt,
                                                 float* __restrict__ C,
                                                 int M, int N, int K) {
  __shared__ ushort As[128 * 64];   // [m][k] 16 KB
  __shared__ ushort Bs[128 * 64];   // [n][k] 16 KB
  int tid = threadIdx.x, wv = tid >> 6, lane = tid & 63;
  int m0 = blockIdx.y * 128, n0 = blockIdx.x * 128;
  int wr = wv >> 1, wc = wv & 1;
  int l15 = lane & 15, l4 = lane >> 4;

  floatx4 acc[4][4];
#pragma unroll
  for (int i = 0; i < 4; ++i)
#pragma unroll
    for (int j = 0; j < 4; ++j) acc[i][j] = 0.0f;

  for (int k0 = 0; k0 < K; k0 += 64) {
#pragma unroll
    for (int it = 0; it < 4; ++it) {
      int ci = (it * 4 + wv) * 64 + lane;        // chunk id 0..1023
      int row = ci >> 3, kc = ci & 7;
      gld_lds16(A + (size_t)(m0 + row) * K + k0 + kc * 8,
                As + (size_t)(it * 4 + wv) * 512);
      gld_lds16(Bt + (size_t)(n0 + row) * K + k0 + kc * 8,
                Bs + (size_t)(it * 4 + wv) * 512);
    }
    __syncthreads();
#pragma unroll
    for (int ks = 0; ks < 2; ++ks) {
      shortx8 af[4], bf[4];
#pragma unroll
      for (int i = 0; i < 4; ++i)
        af[i] = *(const shortx8*)&As[(wr * 64 + i * 16 + l15) * 64 + ks * 32 + l4 * 8];
#pragma unroll
      for (int j = 0; j < 4; ++j)
        bf[j] = *(const shortx8*)&Bs[(wc * 64 + j * 16 + l15) * 64 + ks * 32 + l4 * 8];
#pragma unroll
      for (int i = 0; i < 4; ++i)
#pragma unroll
        for (int j = 0; j < 4; ++j)
          acc[i][j] = __builtin_amdgcn_mfma_f32_16x16x32_bf16(af[i], bf[j], acc[i][j], 0, 0, 0);
    }
    __syncthreads();
  }
#pragma unroll
  for (int i = 0; i < 4; ++i)
#pragma unroll
    for (int j = 0; j < 4; ++j)
#pragma unroll
      for (int r = 0; r < 4; ++r)
        C[(size_t)(m0 + wr * 64 + i * 16 + l4 * 4 + r) * N + n0 + wc * 64 + j * 16 + l15] =
            acc[i][j][r];
}

// ---------------- RoPE in place: head h at x[t*rowstride + h*64 + d] ----------------
__global__ void rope_f32(float* __restrict__ x, int nheads, int rowstride) {
  int idx = blockIdx.x * blockDim.x + threadIdx.x;
  int total = T_SEQ * nheads * 32;
  if (idx >= total) return;
  int i = idx & 31;
  int h = (idx >> 5) % nheads;
  int t = idx / (32 * nheads);
  float inv = powf(10000.0f, -(float)i / 32.0f);
  float f = (float)t * inv;
  float c = cosf(f), s = sinf(f);
  float* p = x + (size_t)t * rowstride + h * DH;
  float x1 = p[i], x2 = p[i + 32];
  p[i]      = x1 * c - x2 * s;
  p[i + 32] = x1 * s + x2 * c;
}

// ---------------- block means (from fused kvg) ----------------
__global__ void cmp_mean(const float* __restrict__ kvg,
                         float* __restrict__ kc, float* __restrict__ vc) {
  int idx = blockIdx.x * blockDim.x + threadIdx.x;  // n*256 + hkv*64 + d
  if (idx >= NBLK * NKV * DH) return;
  int d = idx & 63, hkv = (idx >> 6) & 3, n = idx >> 8;
  float sk = 0.f, sv = 0.f;
  for (int j = 0; j < BSZ; ++j) {
    size_t row = (size_t)(n * BSZ + j) * KVGS;
    sk += kvg[row + hkv * DH + d];
    sv += kvg[row + 256 + hkv * DH + d];
  }
  kc[idx] = sk * (1.0f / 64.0f);
  vc[idx] = sv * (1.0f / 64.0f);
}

__device__ __forceinline__ float wred_sum(float x) {
#pragma unroll
  for (int m = 1; m < 64; m <<= 1) x += __shfl_xor(x, m, 64);
  return x;
}

// ---------------- compressed attention + importance ----------------
__global__ __launch_bounds__(64) void cmp_attn(const float* __restrict__ q,
                                               const float* __restrict__ kc,
                                               const float* __restrict__ vc,
                                               float* __restrict__ ocmp,
                                               float* __restrict__ imp) {
  int h = blockIdx.x & 63;
  int t = blockIdx.x >> 6;
  int lane = threadIdx.x;
  int hkv = h >> 4;
  size_t qoff = ((size_t)t * NH + h) * DH + lane;
  float qd = q[qoff];
  int nv = (t >= 63) ? (((t - 63) >> 6) + 1) : 0;
  if (nv == 0) { ocmp[qoff] = 0.f; return; }
  float s[NBLK];
#pragma unroll
  for (int n = 0; n < NBLK; ++n) {
    float part = (n < nv) ? qd * kc[n * (NKV * DH) + hkv * DH + lane] : 0.f;
    part = wred_sum(part);
    s[n] = part * SCL;
  }
  float m = -INFINITY;
#pragma unroll
  for (int n = 0; n < NBLK; ++n)
    if (n < nv) m = fmaxf(m, s[n]);
  float p[NBLK];
  float denom = 0.f;
#pragma unroll
  for (int n = 0; n < NBLK; ++n) {
    p[n] = (n < nv) ? expf(s[n] - m) : 0.f;
    denom += p[n];
  }
  float rd = 1.0f / denom;
  float od = 0.f;
#pragma unroll
  for (int n = 0; n < NBLK; ++n)
    od = fmaf(p[n] * rd, vc[n * (NKV * DH) + hkv * DH + lane], od);
  ocmp[qoff] = od;
  if (lane < nv) atomicAdd(&imp[((size_t)t * NKV + hkv) * NBLK + lane], p[lane] * rd);
}

// ---------------- top-8 block selection per (t, hkv) ----------------
__global__ void topk_kernel(const float* __restrict__ imp, int* __restrict__ tidx) {
  int idx = blockIdx.x * blockDim.x + threadIdx.x;
  if (idx >= T_SEQ * NKV) return;
  int t = idx >> 2;
  int cur = t >> 6;
  float vals[NBLK];
#pragma unroll
  for (int n = 0; n < NBLK; ++n) {
    float v0;
    if (n > cur) v0 = -INFINITY;
    else if (n == 0 || n == cur) v0 = INFINITY;
    else v0 = imp[(size_t)idx * NBLK + n];
    vals[n] = v0;
  }
  for (int s = 0; s < SSEL; ++s) {
    float best = -INFINITY;
    int bi = -1;
#pragma unroll
    for (int n = 0; n < NBLK; ++n) {
      if (vals[n] > best) { best = vals[n]; bi = n; }
    }
    if (bi >= 0) vals[bi] = -INFINITY;
    tidx[(size_t)idx * SSEL + s] = bi;
  }
}

// ---------------- selection + SWA attention + gated combine (v3) ----------------
// One 256-thread block per (t, hkv). Reads fused kvg; writes bf16 o_attn.
__global__ __launch_bounds__(256) void slc_swa_v3(
    const float* __restrict__ q, const float* __restrict__ kvg,
    const float* __restrict__ ocmp, const int* __restrict__ tidx,
    ushort* __restrict__ obuf) {
  __shared__ __align__(16) float qt[64 * QT_RL];   // [d][h]
  __shared__ __align__(16) float KV[64 * 64];      // Kt / Vs / reduce scratch
  __shared__ __align__(16) float Sb[16 * SB_RL];   // [h][key]
  __shared__ int bselS[SSEL];

  int tid = threadIdx.x;
  int t   = blockIdx.x >> 2;
  int hkv = blockIdx.x & 3;
  int wv  = tid >> 6;
  int lane = tid & 63;
  int hq  = lane >> 4;
  int kq  = lane & 15;

  {
    const float* qrow = q + ((size_t)t * NH + hkv * GQ) * DH;
#pragma unroll
    for (int it = 0; it < 4; ++it) {
      int e = tid + it * 256;
      qt[(e & 63) * QT_RL + (e >> 6)] = qrow[e];
    }
    if (tid < SSEL) bselS[tid] = tidx[((size_t)t * NKV + hkv) * SSEL + tid];
  }
  __syncthreads();

  float o_slc[4][4] = {};
  float o_swa[4][4] = {};

  for (int half = 0; half < 2; ++half) {
    // ================= scores: 8 tiles of 64 keys =================
    for (int s = 0; s < SSEL; ++s) {
      int b = (half == 0) ? bselS[s] : 0;
      int pos0 = (half == 0) ? b * BSZ : (t - (WWIN - 1) + s * BSZ);
      bool active = (half == 1) || (b >= 0);

      if (active) {
        // stage Kt[d][chunk-swizzled j]; lanes span (d,jl) -> conflict-free writes
#pragma unroll
        for (int it = 0; it < 16; ++it) {
          int e = tid + it * 256;
          int jc = e >> 8, dd = (e >> 2) & 63, jl = e & 3;
          int pos = pos0 + jc * 4 + jl;
          float val = 0.f;
          if (pos >= 0) val = kvg[(size_t)pos * KVGS + hkv * DH + dd];
          KV[dd * 64 + ((jc + dd) & 15) * 4 + jl] = val;
        }
      }
      __syncthreads();
      float acc[4][4] = {};
      if (active) {
        int dbase = wv * 16;
#pragma unroll
        for (int dd = 0; dd < 16; ++dd) {
          int d = dbase + dd;
          float4 k4 = *(const float4*)&KV[d * 64 + ((kq + d) & 15) * 4];
          float4 q4 = *(const float4*)&qt[d * QT_RL + hq * 4];
          acc[0][0] = fmaf(q4.x, k4.x, acc[0][0]); acc[0][1] = fmaf(q4.x, k4.y, acc[0][1]);
          acc[0][2] = fmaf(q4.x, k4.z, acc[0][2]); acc[0][3] = fmaf(q4.x, k4.w, acc[0][3]);
          acc[1][0] = fmaf(q4.y, k4.x, acc[1][0]); acc[1][1] = fmaf(q4.y, k4.y, acc[1][1]);
          acc[1][2] = fmaf(q4.y, k4.z, acc[1][2]); acc[1][3] = fmaf(q4.y, k4.w, acc[1][3]);
          acc[2][0] = fmaf(q4.z, k4.x, acc[2][0]); acc[2][1] = fmaf(q4.z, k4.y, acc[2][1]);
          acc[2][2] = fmaf(q4.z, k4.z, acc[2][2]); acc[2][3] = fmaf(q4.z, k4.w, acc[2][3]);
          acc[3][0] = fmaf(q4.w, k4.x, acc[3][0]); acc[3][1] = fmaf(q4.w, k4.y, acc[3][1]);
          acc[3][2] = fmaf(q4.w, k4.z, acc[3][2]); acc[3][3] = fmaf(q4.w, k4.w, acc[3][3]);
        }
      }
      __syncthreads();
      if (active) {
#pragma unroll
        for (int i = 0; i < 4; ++i)
          *(float4*)&KV[(wv * 16 + hq * 4 + i) * 64 + kq * 4] =
              make_float4(acc[i][0], acc[i][1], acc[i][2], acc[i][3]);
      }
      __syncthreads();
      {
        int h = tid >> 4, k4b = (tid & 15) * 4;
        float f[4] = {0.f, 0.f, 0.f, 0.f};
        if (active) {
#pragma unroll
          for (int w = 0; w < 4; ++w) {
            float4 p4 = *(const float4*)&KV[(w * 16 + h) * 64 + k4b];
            f[0] += p4.x; f[1] += p4.y; f[2] += p4.z; f[3] += p4.w;
          }
        }
        float out[4];
#pragma unroll
        for (int i = 0; i < 4; ++i) {
          int pos = pos0 + k4b + i;
          bool valid = active && (pos >= 0) && (pos <= t);
          out[i] = valid ? f[i] * SCL : NEGF;
        }
        *(float4*)&Sb[h * SB_RL + s * 64 + k4b] =
            make_float4(out[0], out[1], out[2], out[3]);
      }
      __syncthreads();
    }

    // ================= softmax over Sb rows [16][512] =================
    {
      int h = tid >> 4, seg = tid & 15;
      float4 r[8];
      float mx = -INFINITY;
#pragma unroll
      for (int c = 0; c < 8; ++c) {
        r[c] = *(const float4*)&Sb[h * SB_RL + seg * 4 + c * 64];
        mx = fmaxf(mx, fmaxf(fmaxf(r[c].x, r[c].y), fmaxf(r[c].z, r[c].w)));
      }
#pragma unroll
      for (int m = 1; m < 16; m <<= 1) mx = fmaxf(mx, __shfl_xor(mx, m, 64));
      float sum = 0.f;
#pragma unroll
      for (int c = 0; c < 8; ++c) {
        r[c].x = expf(r[c].x - mx); r[c].y = expf(r[c].y - mx);
        r[c].z = expf(r[c].z - mx); r[c].w = expf(r[c].w - mx);
        sum += r[c].x + r[c].y + r[c].z + r[c].w;
      }
#pragma unroll
      for (int m = 1; m < 16; m <<= 1) sum += __shfl_xor(sum, m, 64);
      float rd = 1.0f / sum;
#pragma unroll
      for (int c = 0; c < 8; ++c) {
        r[c].x *= rd; r[c].y *= rd; r[c].z *= rd; r[c].w *= rd;
        *(float4*)&Sb[h * SB_RL + seg * 4 + c * 64] = r[c];
      }
    }
    __syncthreads();

    // ================= PV: 8 tiles =================
    for (int s = 0; s < SSEL; ++s) {
      int b = (half == 0) ? bselS[s] : 0;
      int pos0 = (half == 0) ? b * BSZ : (t - (WWIN - 1) + s * BSZ);
      bool active = (half == 1) || (b >= 0);

      if (active) {
#pragma unroll
        for (int it = 0; it < 4; ++it) {
          int e = (tid + it * 256) * 4;
          int j = e >> 6, dd = e & 63;
          int pos = pos0 + j;
          float4 val = make_float4(0.f, 0.f, 0.f, 0.f);
          if (pos >= 0)
            val = *(const float4*)&kvg[(size_t)pos * KVGS + 256 + hkv * DH + dd];
          *(float4*)&KV[j * 64 + dd] = val;
        }
      }
      __syncthreads();
      if (active) {
        int jb = wv * 16;
        int dq = tid & 15;
        float tacc[4][4] = {};
#pragma unroll
        for (int jj = 0; jj < 16; jj += 4) {
          float4 p4[4], v4[4];
#pragma unroll
          for (int i = 0; i < 4; ++i)
            p4[i] = *(const float4*)&Sb[(hq * 4 + i) * SB_RL + s * 64 + jb + jj];
#pragma unroll
          for (int r = 0; r < 4; ++r)
            v4[r] = *(const float4*)&KV[(jb + jj + r) * 64 + dq * 4];
#pragma unroll
          for (int i = 0; i < 4; ++i) {
            tacc[i][0] = fmaf(p4[i].x, v4[0].x, tacc[i][0]);
            tacc[i][1] = fmaf(p4[i].x, v4[0].y, tacc[i][1]);
            tacc[i][2] = fmaf(p4[i].x, v4[0].z, tacc[i][2]);
            tacc[i][3] = fmaf(p4[i].x, v4[0].w, tacc[i][3]);
            tacc[i][0] = fmaf(p4[i].y, v4[1].x, tacc[i][0]);
            tacc[i][1] = fmaf(p4[i].y, v4[1].y, tacc[i][1]);
            tacc[i][2] = fmaf(p4[i].y, v4[1].z, tacc[i][2]);
            tacc[i][3] = fmaf(p4[i].y, v4[1].w, tacc[i][3]);
            tacc[i][0] = fmaf(p4[i].z, v4[2].x, tacc[i][0]);
            tacc[i][1] = fmaf(p4[i].z, v4[2].y, tacc[i][1]);
            tacc[i][2] = fmaf(p4[i].z, v4[2].z, tacc[i][2]);
            tacc[i][3] = fmaf(p4[i].z, v4[2].w, tacc[i][3]);
            tacc[i][0] = fmaf(p4[i].w, v4[3].x, tacc[i][0]);
            tacc[i][1] = fmaf(p4[i].w, v4[3].y, tacc[i][1]);
            tacc[i][2] = fmaf(p4[i].w, v4[3].z, tacc[i][2]);
            tacc[i][3] = fmaf(p4[i].w, v4[3].w, tacc[i][3]);
          }
        }
        if (half == 0) {
#pragma unroll
          for (int i = 0; i < 4; ++i)
#pragma unroll
            for (int c = 0; c < 4; ++c) o_slc[i][c] += tacc[i][c];
        } else {
#pragma unroll
          for (int i = 0; i < 4; ++i)
#pragma unroll
            for (int c = 0; c < 4; ++c) o_swa[i][c] += tacc[i][c];
        }
      }
      __syncthreads();
    }
  }

  // ================= cross-wave O reduction + gated combine =================
  int h = tid >> 4, d4 = (tid & 15) * 4;
  float4 oslc_f, oswa_f;
  {
#pragma unroll
    for (int i = 0; i < 4; ++i)
      *(float4*)&KV[(wv * 16 + hq * 4 + i) * 64 + (tid & 15) * 4] =
          make_float4(o_slc[i][0], o_slc[i][1], o_slc[i][2], o_slc[i][3]);
    __syncthreads();
    oslc_f = make_float4(0.f, 0.f, 0.f, 0.f);
#pragma unroll
    for (int w = 0; w < 4; ++w) {
      float4 p4 = *(const float4*)&KV[(w * 16 + h) * 64 + d4];
      oslc_f.x += p4.x; oslc_f.y += p4.y; oslc_f.z += p4.z; oslc_f.w += p4.w;
    }
    __syncthreads();
#pragma unroll
    for (int i = 0; i < 4; ++i)
      *(float4*)&KV[(wv * 16 + hq * 4 + i) * 64 + (tid & 15) * 4] =
          make_float4(o_swa[i][0], o_swa[i][1], o_swa[i][2], o_swa[i][3]);
    __syncthreads();
    oswa_f = make_float4(0.f, 0.f, 0.f, 0.f);
#pragma unroll
    for (int w = 0; w < 4; ++w) {
      float4 p4 = *(const float4*)&KV[(w * 16 + h) * 64 + d4];
      oswa_f.x += p4.x; oswa_f.y += p4.y; oswa_f.z += p4.z; oswa_f.w += p4.w;
    }
  }

  size_t grow = (size_t)t * KVGS + 512 + (hkv * GQ + h) * 3;
  float g0 = 1.f / (1.f + expf(-kvg[grow + 0]));
  float g1 = 1.f / (1.f + expf(-kvg[grow + 1]));
  float g2 = 1.f / (1.f + expf(-kvg[grow + 2]));
  size_t oo = ((size_t)t * NH + hkv * GQ + h) * DH + d4;
  float4 oc = *(const float4*)&ocmp[oo];
  float rx = g0 * oc.x + g1 * oslc_f.x + g2 * oswa_f.x;
  float ry = g0 * oc.y + g1 * oslc_f.y + g2 * oswa_f.y;
  float rz = g0 * oc.z + g1 * oslc_f.z + g2 * oswa_f.z;
  float rw = g0 * oc.w + g1 * oslc_f.w + g2 * oswa_f.w;
  ushort4 r16;
  r16.x = f2bf(rx); r16.y = f2bf(ry); r16.z = f2bf(rz); r16.w = f2bf(rw);
  *(ushort4*)&obuf[oo] = r16;
}

extern "C" void kernel_launch(void* const* d_in, const int* in_sizes, int n_in,
                              void* d_out, int out_size, void* d_ws, size_t ws_size,
                              hipStream_t stream) {
  const float* x  = (const float*)d_in[0];
  const float* Wq = (const float*)d_in[1];
  const float* Wk = (const float*)d_in[2];
  const float* Wv = (const float*)d_in[3];
  const float* Wg = (const float*)d_in[4];
  const float* Wo = (const float*)d_in[5];
  float* out = (float*)d_out;

  char* p = (char*)d_ws;
  ushort* xb    = (ushort*)p;  p += (size_t)1024 * 2048 * 2;   // 4 MB
  ushort* WT    = (ushort*)p;  p += (size_t)4096 * 2048 * 2;   // 16 MB (WqT, later WoT)
  ushort* Wkvg  = (ushort*)p;  p += (size_t)768  * 2048 * 2;   // 3 MB
  float*  qbuf  = (float*)p;   p += (size_t)1024 * 4096 * 4;   // 16 MB
  float*  kvg   = (float*)p;   p += (size_t)1024 * KVGS * 4;   // 3 MB
  float*  ocmp  = (float*)p;   p += (size_t)1024 * 4096 * 4;   // 16 MB
  ushort* obuf  = (ushort*)p;  p += (size_t)1024 * 4096 * 2;   // 8 MB
  float*  impb  = (float*)p;   p += (size_t)65536 * 4;
  int*    tidx  = (int*)p;     p += (size_t)32768 * 4;
  float*  kc    = (float*)p;   p += (size_t)4096 * 4;
  float*  vc    = (float*)p;   p += (size_t)4096 * 4;

  hipMemsetAsync(impb, 0, 65536 * sizeof(float), stream);
  // zero pad rows 704..767 of fused Bt (bf16 zero == 0x0000)
  hipMemsetAsync(Wkvg + (size_t)704 * 2048, 0, (size_t)64 * 2048 * 2, stream);

  // casts
  cast_x<<<2048, 256, 0, stream>>>(x, xb, 1024 * 2048 / 4);
  cast_tr<<<dim3(4096 / 32, 2048 / 32), 256, 0, stream>>>(Wq, WT, 2048, 4096);
  cast_tr<<<dim3(256 / 32, 2048 / 32), 256, 0, stream>>>(Wk, Wkvg, 2048, 256);
  cast_tr<<<dim3(256 / 32, 2048 / 32), 256, 0, stream>>>(Wv, Wkvg + (size_t)256 * 2048, 2048, 256);
  cast_tr<<<dim3(192 / 32, 2048 / 32), 256, 0, stream>>>(Wg, Wkvg + (size_t)512 * 2048, 2048, 192);

  // projections (MFMA)
  gemm_bf16<<<dim3(4096 / 128, 1024 / 128), 256, 0, stream>>>(xb, WT, qbuf, 1024, 4096, 2048);
  gemm_bf16<<<dim3(KVGS / 128, 1024 / 128), 256, 0, stream>>>(xb, Wkvg, kvg, 1024, KVGS, 2048);

  // rope
  rope_f32<<<(T_SEQ * NH * 32 + 255) / 256, 256, 0, stream>>>(qbuf, NH, 4096);
  rope_f32<<<(T_SEQ * NKV * 32 + 255) / 256, 256, 0, stream>>>(kvg, NKV, KVGS);

  // compressed path
  cmp_mean<<<(NBLK * NKV * DH + 255) / 256, 256, 0, stream>>>(kvg, kc, vc);
  cmp_attn<<<T_SEQ * NH, 64, 0, stream>>>(qbuf, kc, vc, ocmp, impb);
  topk_kernel<<<(T_SEQ * NKV + 255) / 256, 256, 0, stream>>>(impb, tidx);

  // selection + swa + combine -> bf16
  slc_swa_v3<<<T_SEQ * NKV, 256, 0, stream>>>(qbuf, kvg, ocmp, tidx, obuf);

  // output projection (MFMA): cast-transpose Wo into WT (safe: stream-ordered after q GEMM)
  cast_tr<<<dim3(2048 / 32, 4096 / 32), 256, 0, stream>>>(Wo, WT, 4096, 2048);
  gemm_bf16<<<dim3(2048 / 128, 1024 / 128), 256, 0, stream>>>(obuf, WT, out, 1024, 2048, 4096);
}

// Round 6
// 512.152 us; speedup vs baseline: 6.2675x; 1.8552x over previous
//
// R5: MFMA-based slc/swa attention (v4). See theory in commit message.
#include <hip/hip_runtime.h>
#include <hip/hip_bf16.h>
#include <math.h>

#define T_SEQ 1024
#define HIDN  2048
#define NH    64
#define NKV   4
#define DH    64
#define GQ    16
#define BSZ   64
#define NBLK  16
#define SSEL  8
#define WWIN  512
#define SCL   0.125f
#define NEGF  -1e30f

#define KVGS  768    // fused k|v|g row stride (k:0-255, v:256-511, g:512-703, pad)
#define SB_RL 644    // 640 score cols + pad (fp32)
#define PB_RL 648    // 640 prob cols + pad (bf16)
#define NTS   10     // score tiles per half (640 cols)
#define NTP   9      // pv tiles per half

typedef float  floatx4 __attribute__((ext_vector_type(4)));
typedef short  shortx8 __attribute__((ext_vector_type(8)));

__device__ __forceinline__ ushort f2bf(float f) {
  union { float f; unsigned u; } v; v.f = f;
  unsigned r = v.u + 0x7FFF + ((v.u >> 16) & 1);   // RNE
  return (ushort)(r >> 16);
}

__device__ __forceinline__ void gld_lds16(const ushort* g, ushort* l) {
  __builtin_amdgcn_global_load_lds((const __attribute__((address_space(1))) void*)g,
                                   (__attribute__((address_space(3))) void*)l, 16, 0, 0);
}

// ---------------- cast fp32 -> bf16 (elementwise, float4) ----------------
__global__ void cast_x(const float* __restrict__ in, ushort* __restrict__ out, int n4) {
  int i = blockIdx.x * blockDim.x + threadIdx.x;
  if (i >= n4) return;
  float4 f = ((const float4*)in)[i];
  ushort4 u;
  u.x = f2bf(f.x); u.y = f2bf(f.y); u.z = f2bf(f.z); u.w = f2bf(f.w);
  ((ushort4*)out)[i] = u;
}

// ---------------- cast+transpose: in fp32 [K][N] -> out bf16 [N][K] ----------------
__global__ __launch_bounds__(256) void cast_tr(const float* __restrict__ in,
                                               ushort* __restrict__ out, int K, int N) {
  __shared__ float tile[32][33];
  int k0 = blockIdx.y * 32, n0 = blockIdx.x * 32;
  int tx = threadIdx.x & 31, ty = threadIdx.x >> 5;
#pragma unroll
  for (int r = 0; r < 32; r += 8)
    tile[ty + r][tx] = in[(size_t)(k0 + ty + r) * N + n0 + tx];
  __syncthreads();
#pragma unroll
  for (int r = 0; r < 32; r += 8)
    out[(size_t)(n0 + ty + r) * K + k0 + tx] = f2bf(tile[tx][ty + r]);
}

// ---------------- bf16 MFMA GEMM: C[M][N] = A[M][K] @ Bt[N][K]^T ----------------
__global__ __launch_bounds__(256) void gemm_bf16(const ushort* __restrict__ A,
                                                 const ushort* __restrict__ Bt,
                                                 float* __restrict__ C,
                                                 int M, int N, int K) {
  __shared__ ushort As[128 * 64];
  __shared__ ushort Bs[128 * 64];
  int tid = threadIdx.x, wv = tid >> 6, lane = tid & 63;
  int m0 = blockIdx.y * 128, n0 = blockIdx.x * 128;
  int wr = wv >> 1, wc = wv & 1;
  int l15 = lane & 15, l4 = lane >> 4;

  floatx4 acc[4][4];
#pragma unroll
  for (int i = 0; i < 4; ++i)
#pragma unroll
    for (int j = 0; j < 4; ++j) acc[i][j] = 0.0f;

  for (int k0 = 0; k0 < K; k0 += 64) {
#pragma unroll
    for (int it = 0; it < 4; ++it) {
      int ci = (it * 4 + wv) * 64 + lane;
      int row = ci >> 3, kc = ci & 7;
      gld_lds16(A + (size_t)(m0 + row) * K + k0 + kc * 8,
                As + (size_t)(it * 4 + wv) * 512);
      gld_lds16(Bt + (size_t)(n0 + row) * K + k0 + kc * 8,
                Bs + (size_t)(it * 4 + wv) * 512);
    }
    __syncthreads();
#pragma unroll
    for (int ks = 0; ks < 2; ++ks) {
      shortx8 af[4], bf[4];
#pragma unroll
      for (int i = 0; i < 4; ++i)
        af[i] = *(const shortx8*)&As[(wr * 64 + i * 16 + l15) * 64 + ks * 32 + l4 * 8];
#pragma unroll
      for (int j = 0; j < 4; ++j)
        bf[j] = *(const shortx8*)&Bs[(wc * 64 + j * 16 + l15) * 64 + ks * 32 + l4 * 8];
#pragma unroll
      for (int i = 0; i < 4; ++i)
#pragma unroll
        for (int j = 0; j < 4; ++j)
          acc[i][j] = __builtin_amdgcn_mfma_f32_16x16x32_bf16(af[i], bf[j], acc[i][j], 0, 0, 0);
    }
    __syncthreads();
  }
#pragma unroll
  for (int i = 0; i < 4; ++i)
#pragma unroll
    for (int j = 0; j < 4; ++j)
#pragma unroll
      for (int r = 0; r < 4; ++r)
        C[(size_t)(m0 + wr * 64 + i * 16 + l4 * 4 + r) * N + n0 + wc * 64 + j * 16 + l15] =
            acc[i][j][r];
}

// ---------------- RoPE in place ----------------
__global__ void rope_f32(float* __restrict__ x, int nheads, int rowstride) {
  int idx = blockIdx.x * blockDim.x + threadIdx.x;
  int total = T_SEQ * nheads * 32;
  if (idx >= total) return;
  int i = idx & 31;
  int h = (idx >> 5) % nheads;
  int t = idx / (32 * nheads);
  float inv = powf(10000.0f, -(float)i / 32.0f);
  float f = (float)t * inv;
  float c = cosf(f), s = sinf(f);
  float* p = x + (size_t)t * rowstride + h * DH;
  float x1 = p[i], x2 = p[i + 32];
  p[i]      = x1 * c - x2 * s;
  p[i + 32] = x1 * s + x2 * c;
}

// ---------------- K (roped) -> bf16 global kb[t][256] ----------------
__global__ void cast_kb(const float* __restrict__ kvg, ushort* __restrict__ kb) {
  int i = blockIdx.x * blockDim.x + threadIdx.x;   // over 1024*256/4
  if (i >= T_SEQ * 256 / 4) return;
  int t = i >> 6, c4 = (i & 63) * 4;
  float4 f = *(const float4*)&kvg[(size_t)t * KVGS + c4];
  ushort4 u;
  u.x = f2bf(f.x); u.y = f2bf(f.y); u.z = f2bf(f.z); u.w = f2bf(f.w);
  *(ushort4*)&kb[(size_t)t * 256 + c4] = u;
}

// ---------------- V -> bf16 transposed global vtg[d(256)][t(1024)] ----------------
__global__ __launch_bounds__(256) void vt_tr(const float* __restrict__ kvg,
                                             ushort* __restrict__ vtg) {
  __shared__ float tile[32][33];
  int t0 = blockIdx.x * 32, d0 = blockIdx.y * 32;
  int tx = threadIdx.x & 31, ty = threadIdx.x >> 5;
#pragma unroll
  for (int r = 0; r < 32; r += 8)
    tile[ty + r][tx] = kvg[(size_t)(t0 + ty + r) * KVGS + 256 + d0 + tx];
  __syncthreads();
#pragma unroll
  for (int r = 0; r < 32; r += 8)
    vtg[(size_t)(d0 + ty + r) * T_SEQ + t0 + tx] = f2bf(tile[tx][ty + r]);
}

// ---------------- block means (from fused kvg) ----------------
__global__ void cmp_mean(const float* __restrict__ kvg,
                         float* __restrict__ kc, float* __restrict__ vc) {
  int idx = blockIdx.x * blockDim.x + threadIdx.x;
  if (idx >= NBLK * NKV * DH) return;
  int d = idx & 63, hkv = (idx >> 6) & 3, n = idx >> 8;
  float sk = 0.f, sv = 0.f;
  for (int j = 0; j < BSZ; ++j) {
    size_t row = (size_t)(n * BSZ + j) * KVGS;
    sk += kvg[row + hkv * DH + d];
    sv += kvg[row + 256 + hkv * DH + d];
  }
  kc[idx] = sk * (1.0f / 64.0f);
  vc[idx] = sv * (1.0f / 64.0f);
}

__device__ __forceinline__ float wred_sum(float x) {
#pragma unroll
  for (int m = 1; m < 64; m <<= 1) x += __shfl_xor(x, m, 64);
  return x;
}

// ---------------- compressed attention + importance ----------------
__global__ __launch_bounds__(64) void cmp_attn(const float* __restrict__ q,
                                               const float* __restrict__ kc,
                                               const float* __restrict__ vc,
                                               float* __restrict__ ocmp,
                                               float* __restrict__ imp) {
  int h = blockIdx.x & 63;
  int t = blockIdx.x >> 6;
  int lane = threadIdx.x;
  int hkv = h >> 4;
  size_t qoff = ((size_t)t * NH + h) * DH + lane;
  float qd = q[qoff];
  int nv = (t >= 63) ? (((t - 63) >> 6) + 1) : 0;
  if (nv == 0) { ocmp[qoff] = 0.f; return; }
  float s[NBLK];
#pragma unroll
  for (int n = 0; n < NBLK; ++n) {
    float part = (n < nv) ? qd * kc[n * (NKV * DH) + hkv * DH + lane] : 0.f;
    part = wred_sum(part);
    s[n] = part * SCL;
  }
  float m = -INFINITY;
#pragma unroll
  for (int n = 0; n < NBLK; ++n)
    if (n < nv) m = fmaxf(m, s[n]);
  float p[NBLK];
  float denom = 0.f;
#pragma unroll
  for (int n = 0; n < NBLK; ++n) {
    p[n] = (n < nv) ? expf(s[n] - m) : 0.f;
    denom += p[n];
  }
  float rd = 1.0f / denom;
  float od = 0.f;
#pragma unroll
  for (int n = 0; n < NBLK; ++n)
    od = fmaf(p[n] * rd, vc[n * (NKV * DH) + hkv * DH + lane], od);
  ocmp[qoff] = od;
  if (lane < nv) atomicAdd(&imp[((size_t)t * NKV + hkv) * NBLK + lane], p[lane] * rd);
}

// ---------------- top-8 block selection per (t, hkv) ----------------
__global__ void topk_kernel(const float* __restrict__ imp, int* __restrict__ tidx) {
  int idx = blockIdx.x * blockDim.x + threadIdx.x;
  if (idx >= T_SEQ * NKV) return;
  int t = idx >> 2;
  int cur = t >> 6;
  float vals[NBLK];
#pragma unroll
  for (int n = 0; n < NBLK; ++n) {
    float v0;
    if (n > cur) v0 = -INFINITY;
    else if (n == 0 || n == cur) v0 = INFINITY;
    else v0 = imp[(size_t)idx * NBLK + n];
    vals[n] = v0;
  }
  for (int s = 0; s < SSEL; ++s) {
    float best = -INFINITY;
    int bi = -1;
#pragma unroll
    for (int n = 0; n < NBLK; ++n) {
      if (vals[n] > best) { best = vals[n]; bi = n; }
    }
    if (bi >= 0) vals[bi] = -INFINITY;
    tidx[(size_t)idx * SSEL + s] = bi;
  }
}

// ---------------- selection + SWA attention via MFMA (v4) ----------------
// One 256-thread block per (t, hkv); 16 group heads together.
// Scores: D[16h][16k] = Q(A,reg) x K(B,LDS bf16 swizzled). Softmax fp32 in Sb.
// Probs bf16 in Pb (aliased over Sb, barrier-separated). PV: D[16h][16d] =
// P(A, Pb) x Vt(B, LDS from pre-transposed global vtg). SWA tiles are aligned
// absolute 64-blocks (<=9) + band mask, so all staging loads are 16B aligned.
__global__ __launch_bounds__(256) void slc_swa_v4(
    const float* __restrict__ q, const float* __restrict__ kvg,
    const ushort* __restrict__ kb, const ushort* __restrict__ vtg,
    const float* __restrict__ ocmp, const int* __restrict__ tidx,
    ushort* __restrict__ obuf) {
  __shared__ __align__(16) float Sb[16 * SB_RL];   // 41.2 KB (Pb aliased)
  __shared__ __align__(16) ushort Kt[64 * 64];     // 8 KB K/V tile, swizzled
  __shared__ __align__(16) ushort Qs[16 * 72];     // 2.3 KB Q bf16, padded
  __shared__ int bselS[SSEL];
  ushort* Pb = (ushort*)Sb;

  int tid = threadIdx.x;
  int t = blockIdx.x >> 2, hkv = blockIdx.x & 3;
  int wv = tid >> 6, lane = tid & 63;
  int l15 = lane & 15, quad = lane >> 4;

  // stage Q bf16 [16 h][64 d] (pitch 72) + bsel
  {
    int h = tid >> 4, d4 = (tid & 15) * 4;
    float4 f = *(const float4*)&q[(size_t)t * 4096 + (hkv * GQ + h) * 64 + d4];
    ushort4 u;
    u.x = f2bf(f.x); u.y = f2bf(f.y); u.z = f2bf(f.z); u.w = f2bf(f.w);
    *(ushort4*)&Qs[h * 72 + d4] = u;
    if (tid < SSEL) bselS[tid] = tidx[((size_t)t * NKV + hkv) * SSEL + tid];
  }
  __syncthreads();

  // Q A-fragments (same for all waves): m = l15 (head), k = ks*32 + quad*8 + j
  shortx8 qf0 = *(const shortx8*)&Qs[l15 * 72 + quad * 8];
  shortx8 qf1 = *(const shortx8*)&Qs[l15 * 72 + 32 + quad * 8];

  int lo = t - (WWIN - 1); if (lo < 0) lo = 0;
  int blo = lo >> 6, bhi = t >> 6;     // swa covers aligned blocks blo..bhi (<=9)

  floatx4 o_acc[2];
  o_acc[0] = 0.0f; o_acc[1] = 0.0f;

  for (int half = 0; half < 2; ++half) {
    // ========== scores: NTS tiles of 64 keys ==========
    for (int s = 0; s < NTS; ++s) {
      int b = -1;
      if (half == 0) { if (s < SSEL) b = bselS[s]; }
      else           { if (blo + s <= bhi) b = blo + s; }
      bool active = (b >= 0);
      int pos0 = b * BSZ;
      if (active) {
#pragma unroll
        for (int it = 0; it < 2; ++it) {
          int e = tid + it * 256;            // 512 chunks: key=e>>3, c=e&7
          int key = e >> 3, c = e & 7;
          shortx8 val = *(const shortx8*)&kb[(size_t)(pos0 + key) * 256 + hkv * 64 + c * 8];
          *(shortx8*)&Kt[key * 64 + ((c + key) & 7) * 8] = val;
        }
      }
      __syncthreads();
      int colg = s * 64 + wv * 16 + l15;
      float vals[4];
      if (active) {
        int krow = wv * 16 + l15;
        shortx8 kf0 = *(const shortx8*)&Kt[krow * 64 + ((quad + krow) & 7) * 8];
        shortx8 kf1 = *(const shortx8*)&Kt[krow * 64 + ((4 + quad + krow) & 7) * 8];
        floatx4 d = 0.0f;
        d = __builtin_amdgcn_mfma_f32_16x16x32_bf16(qf0, kf0, d, 0, 0, 0);
        d = __builtin_amdgcn_mfma_f32_16x16x32_bf16(qf1, kf1, d, 0, 0, 0);
        int pos = pos0 + wv * 16 + l15;
        bool valid = (pos <= t) && ((half == 0) || (pos >= t - (WWIN - 1)));
#pragma unroll
        for (int r = 0; r < 4; ++r) vals[r] = valid ? d[r] * SCL : NEGF;
      } else {
#pragma unroll
        for (int r = 0; r < 4; ++r) vals[r] = NEGF;
      }
#pragma unroll
      for (int r = 0; r < 4; ++r) Sb[(quad * 4 + r) * SB_RL + colg] = vals[r];
      __syncthreads();
    }

    // ========== softmax over 640 cols, write probs bf16 into Pb (aliased) ==========
    {
      int h = tid >> 4, seg = tid & 15;
      float4 r[NTS];
      float mx = -INFINITY;
#pragma unroll
      for (int c = 0; c < NTS; ++c) {
        r[c] = *(const float4*)&Sb[h * SB_RL + seg * 4 + c * 64];
        mx = fmaxf(mx, fmaxf(fmaxf(r[c].x, r[c].y), fmaxf(r[c].z, r[c].w)));
      }
#pragma unroll
      for (int m = 1; m < 16; m <<= 1) mx = fmaxf(mx, __shfl_xor(mx, m, 64));
      float sum = 0.f;
#pragma unroll
      for (int c = 0; c < NTS; ++c) {
        r[c].x = expf(r[c].x - mx); r[c].y = expf(r[c].y - mx);
        r[c].z = expf(r[c].z - mx); r[c].w = expf(r[c].w - mx);
        sum += r[c].x + r[c].y + r[c].z + r[c].w;
      }
#pragma unroll
      for (int m = 1; m < 16; m <<= 1) sum += __shfl_xor(sum, m, 64);
      float rd = 1.0f / sum;
      __syncthreads();   // all Sb fp32 reads complete before Pb overwrites
#pragma unroll
      for (int c = 0; c < NTS; ++c) {
        ushort4 u;
        u.x = f2bf(r[c].x * rd); u.y = f2bf(r[c].y * rd);
        u.z = f2bf(r[c].z * rd); u.w = f2bf(r[c].w * rd);
        *(ushort4*)&Pb[h * PB_RL + seg * 4 + c * 64] = u;
      }
    }
    __syncthreads();

    // ========== PV: NTP tiles ==========
    for (int s = 0; s < NTP; ++s) {
      int b = -1;
      if (half == 0) { if (s < SSEL) b = bselS[s]; }
      else           { if (blo + s <= bhi) b = blo + s; }
      bool active = (b >= 0);
      int pos0 = b * BSZ;
      if (active) {
#pragma unroll
        for (int it = 0; it < 2; ++it) {
          int e = tid + it * 256;            // 512 chunks: d=e>>3, c=e&7
          int dd = e >> 3, c = e & 7;
          shortx8 val = *(const shortx8*)&vtg[(size_t)(hkv * 64 + dd) * T_SEQ + pos0 + c * 8];
          *(shortx8*)&Kt[dd * 64 + ((c + dd) & 7) * 8] = val;
        }
      }
      __syncthreads();
      if (active) {
        shortx8 pf0 = *(const shortx8*)&Pb[l15 * PB_RL + s * 64 + quad * 8];
        shortx8 pf1 = *(const shortx8*)&Pb[l15 * PB_RL + s * 64 + 32 + quad * 8];
        int vrow = wv * 16 + l15;
        shortx8 vf0 = *(const shortx8*)&Kt[vrow * 64 + ((quad + vrow) & 7) * 8];
        shortx8 vf1 = *(const shortx8*)&Kt[vrow * 64 + ((4 + quad + vrow) & 7) * 8];
        o_acc[half] = __builtin_amdgcn_mfma_f32_16x16x32_bf16(pf0, vf0, o_acc[half], 0, 0, 0);
        o_acc[half] = __builtin_amdgcn_mfma_f32_16x16x32_bf16(pf1, vf1, o_acc[half], 0, 0, 0);
      }
      __syncthreads();
    }
  }

  // ========== gated combine; dims are wave-disjoint, no cross-wave reduce ==========
  int dim = wv * 16 + l15;
#pragma unroll
  for (int r = 0; r < 4; ++r) {
    int gh = hkv * GQ + quad * 4 + r;
    size_t grow = (size_t)t * KVGS + 512 + gh * 3;
    float g0 = 1.f / (1.f + expf(-kvg[grow + 0]));
    float g1 = 1.f / (1.f + expf(-kvg[grow + 1]));
    float g2 = 1.f / (1.f + expf(-kvg[grow + 2]));
    size_t oo = (size_t)t * 4096 + gh * 64 + dim;
    float res = g0 * ocmp[oo] + g1 * o_acc[0][r] + g2 * o_acc[1][r];
    obuf[oo] = f2bf(res);
  }
}

extern "C" void kernel_launch(void* const* d_in, const int* in_sizes, int n_in,
                              void* d_out, int out_size, void* d_ws, size_t ws_size,
                              hipStream_t stream) {
  const float* x  = (const float*)d_in[0];
  const float* Wq = (const float*)d_in[1];
  const float* Wk = (const float*)d_in[2];
  const float* Wv = (const float*)d_in[3];
  const float* Wg = (const float*)d_in[4];
  const float* Wo = (const float*)d_in[5];
  float* out = (float*)d_out;

  char* p = (char*)d_ws;
  ushort* xb    = (ushort*)p;  p += (size_t)1024 * 2048 * 2;
  ushort* WT    = (ushort*)p;  p += (size_t)4096 * 2048 * 2;   // WqT, later WoT
  ushort* Wkvg  = (ushort*)p;  p += (size_t)768  * 2048 * 2;
  float*  qbuf  = (float*)p;   p += (size_t)1024 * 4096 * 4;
  float*  kvg   = (float*)p;   p += (size_t)1024 * KVGS * 4;
  float*  ocmp  = (float*)p;   p += (size_t)1024 * 4096 * 4;
  ushort* obuf  = (ushort*)p;  p += (size_t)1024 * 4096 * 2;
  float*  impb  = (float*)p;   p += (size_t)65536 * 4;
  int*    tidx  = (int*)p;     p += (size_t)32768 * 4;
  float*  kc    = (float*)p;   p += (size_t)4096 * 4;
  float*  vc    = (float*)p;   p += (size_t)4096 * 4;
  ushort* kb    = (ushort*)p;  p += (size_t)1024 * 256 * 2;    // bf16 roped K
  ushort* vtg   = (ushort*)p;  p += (size_t)256 * 1024 * 2;    // bf16 V^T [d][t]

  hipMemsetAsync(impb, 0, 65536 * sizeof(float), stream);
  hipMemsetAsync(Wkvg + (size_t)704 * 2048, 0, (size_t)64 * 2048 * 2, stream);

  // casts
  cast_x<<<2048, 256, 0, stream>>>(x, xb, 1024 * 2048 / 4);
  cast_tr<<<dim3(4096 / 32, 2048 / 32), 256, 0, stream>>>(Wq, WT, 2048, 4096);
  cast_tr<<<dim3(256 / 32, 2048 / 32), 256, 0, stream>>>(Wk, Wkvg, 2048, 256);
  cast_tr<<<dim3(256 / 32, 2048 / 32), 256, 0, stream>>>(Wv, Wkvg + (size_t)256 * 2048, 2048, 256);
  cast_tr<<<dim3(192 / 32, 2048 / 32), 256, 0, stream>>>(Wg, Wkvg + (size_t)512 * 2048, 2048, 192);

  // projections (MFMA)
  gemm_bf16<<<dim3(4096 / 128, 1024 / 128), 256, 0, stream>>>(xb, WT, qbuf, 1024, 4096, 2048);
  gemm_bf16<<<dim3(KVGS / 128, 1024 / 128), 256, 0, stream>>>(xb, Wkvg, kvg, 1024, KVGS, 2048);

  // rope
  rope_f32<<<(T_SEQ * NH * 32 + 255) / 256, 256, 0, stream>>>(qbuf, NH, 4096);
  rope_f32<<<(T_SEQ * NKV * 32 + 255) / 256, 256, 0, stream>>>(kvg, NKV, KVGS);

  // bf16 K + transposed V for MFMA attention
  cast_kb<<<(T_SEQ * 256 / 4 + 255) / 256, 256, 0, stream>>>(kvg, kb);
  vt_tr<<<dim3(T_SEQ / 32, 256 / 32), 256, 0, stream>>>(kvg, vtg);

  // compressed path
  cmp_mean<<<(NBLK * NKV * DH + 255) / 256, 256, 0, stream>>>(kvg, kc, vc);
  cmp_attn<<<T_SEQ * NH, 64, 0, stream>>>(qbuf, kc, vc, ocmp, impb);
  topk_kernel<<<(T_SEQ * NKV + 255) / 256, 256, 0, stream>>>(impb, tidx);

  // selection + swa + combine -> bf16
  slc_swa_v4<<<T_SEQ * NKV, 256, 0, stream>>>(qbuf, kvg, kb, vtg, ocmp, tidx, obuf);

  // output projection (MFMA)
  cast_tr<<<dim3(2048 / 32, 4096 / 32), 256, 0, stream>>>(Wo, WT, 4096, 2048);
  gemm_bf16<<<dim3(2048 / 128, 1024 / 128), 256, 0, stream>>>(obuf, WT, out, 1024, 2048, 4096);
}

// Round 7
// 494.756 us; speedup vs baseline: 6.4879x; 1.0352x over previous
//
// R6: slc_swa_v5 — wave-owns-tile, direct global->register K/V fragments,
// gate-folded single accumulator, ~10 barriers/block. GEMMs 64x128 tiles.
#include <hip/hip_runtime.h>
#include <hip/hip_bf16.h>
#include <math.h>

#define T_SEQ 1024
#define HIDN  2048
#define NH    64
#define NKV   4
#define DH    64
#define GQ    16
#define BSZ   64
#define NBLK  16
#define SSEL  8
#define WWIN  512
#define SCL   0.125f
#define NEGF  -1e30f

#define KVGS  768    // fused k|v|g row stride (k:0-255, v:256-511, g:512-703, pad)
#define SB_RL 644    // 640 score cols + pad (fp32)
#define PB_RL 648    // 640 prob cols + pad (bf16)
#define NTS   10     // tiles per half (640 cols)

typedef float  floatx4 __attribute__((ext_vector_type(4)));
typedef short  shortx8 __attribute__((ext_vector_type(8)));

__device__ __forceinline__ ushort f2bf(float f) {
  union { float f; unsigned u; } v; v.f = f;
  unsigned r = v.u + 0x7FFF + ((v.u >> 16) & 1);   // RNE
  return (ushort)(r >> 16);
}

__device__ __forceinline__ void gld_lds16(const ushort* g, ushort* l) {
  __builtin_amdgcn_global_load_lds((const __attribute__((address_space(1))) void*)g,
                                   (__attribute__((address_space(3))) void*)l, 16, 0, 0);
}

// ---------------- cast fp32 -> bf16 ----------------
__global__ void cast_x(const float* __restrict__ in, ushort* __restrict__ out, int n4) {
  int i = blockIdx.x * blockDim.x + threadIdx.x;
  if (i >= n4) return;
  float4 f = ((const float4*)in)[i];
  ushort4 u;
  u.x = f2bf(f.x); u.y = f2bf(f.y); u.z = f2bf(f.z); u.w = f2bf(f.w);
  ((ushort4*)out)[i] = u;
}

// ---------------- cast+transpose: fp32 [K][N] -> bf16 [N][K] ----------------
__global__ __launch_bounds__(256) void cast_tr(const float* __restrict__ in,
                                               ushort* __restrict__ out, int K, int N) {
  __shared__ float tile[32][33];
  int k0 = blockIdx.y * 32, n0 = blockIdx.x * 32;
  int tx = threadIdx.x & 31, ty = threadIdx.x >> 5;
#pragma unroll
  for (int r = 0; r < 32; r += 8)
    tile[ty + r][tx] = in[(size_t)(k0 + ty + r) * N + n0 + tx];
  __syncthreads();
#pragma unroll
  for (int r = 0; r < 32; r += 8)
    out[(size_t)(n0 + ty + r) * K + k0 + tx] = f2bf(tile[tx][ty + r]);
}

// ---------------- bf16 MFMA GEMM, BM=64 BN=128 BK=64 ----------------
// C[M][N] = A[M][K] @ Bt[N][K]^T. 256 thr = 4 waves; wave w: n = w*32..+31.
__global__ __launch_bounds__(256) void gemm_bf16_64(const ushort* __restrict__ A,
                                                    const ushort* __restrict__ Bt,
                                                    float* __restrict__ C,
                                                    int M, int N, int K) {
  __shared__ ushort As[64 * 64];    // 8 KB
  __shared__ ushort Bs[128 * 64];   // 16 KB
  int tid = threadIdx.x, wv = tid >> 6, lane = tid & 63;
  int m0 = blockIdx.y * 64, n0 = blockIdx.x * 128;
  int l15 = lane & 15, l4 = lane >> 4;

  floatx4 acc[4][2];
#pragma unroll
  for (int i = 0; i < 4; ++i)
#pragma unroll
    for (int j = 0; j < 2; ++j) acc[i][j] = 0.0f;

  for (int k0 = 0; k0 < K; k0 += 64) {
#pragma unroll
    for (int it = 0; it < 2; ++it) {
      int ci = (it * 4 + wv) * 64 + lane;          // A: 512 chunks
      gld_lds16(A + (size_t)(m0 + (ci >> 3)) * K + k0 + (ci & 7) * 8,
                As + (size_t)(it * 4 + wv) * 512);
    }
#pragma unroll
    for (int it = 0; it < 4; ++it) {
      int ci = (it * 4 + wv) * 64 + lane;          // B: 1024 chunks
      gld_lds16(Bt + (size_t)(n0 + (ci >> 3)) * K + k0 + (ci & 7) * 8,
                Bs + (size_t)(it * 4 + wv) * 512);
    }
    __syncthreads();
#pragma unroll
    for (int ks = 0; ks < 2; ++ks) {
      shortx8 af[4], bf[2];
#pragma unroll
      for (int i = 0; i < 4; ++i)
        af[i] = *(const shortx8*)&As[(i * 16 + l15) * 64 + ks * 32 + l4 * 8];
#pragma unroll
      for (int j = 0; j < 2; ++j)
        bf[j] = *(const shortx8*)&Bs[(wv * 32 + j * 16 + l15) * 64 + ks * 32 + l4 * 8];
#pragma unroll
      for (int i = 0; i < 4; ++i)
#pragma unroll
        for (int j = 0; j < 2; ++j)
          acc[i][j] = __builtin_amdgcn_mfma_f32_16x16x32_bf16(af[i], bf[j], acc[i][j], 0, 0, 0);
    }
    __syncthreads();
  }
#pragma unroll
  for (int i = 0; i < 4; ++i)
#pragma unroll
    for (int j = 0; j < 2; ++j)
#pragma unroll
      for (int r = 0; r < 4; ++r)
        C[(size_t)(m0 + i * 16 + l4 * 4 + r) * N + n0 + wv * 32 + j * 16 + l15] =
            acc[i][j][r];
}

// ---------------- RoPE in place ----------------
__global__ void rope_f32(float* __restrict__ x, int nheads, int rowstride) {
  int idx = blockIdx.x * blockDim.x + threadIdx.x;
  int total = T_SEQ * nheads * 32;
  if (idx >= total) return;
  int i = idx & 31;
  int h = (idx >> 5) % nheads;
  int t = idx / (32 * nheads);
  float inv = powf(10000.0f, -(float)i / 32.0f);
  float f = (float)t * inv;
  float c = cosf(f), s = sinf(f);
  float* p = x + (size_t)t * rowstride + h * DH;
  float x1 = p[i], x2 = p[i + 32];
  p[i]      = x1 * c - x2 * s;
  p[i + 32] = x1 * s + x2 * c;
}

// ---------------- K (roped) -> bf16 kb[t][256] ----------------
__global__ void cast_kb(const float* __restrict__ kvg, ushort* __restrict__ kb) {
  int i = blockIdx.x * blockDim.x + threadIdx.x;
  if (i >= T_SEQ * 256 / 4) return;
  int t = i >> 6, c4 = (i & 63) * 4;
  float4 f = *(const float4*)&kvg[(size_t)t * KVGS + c4];
  ushort4 u;
  u.x = f2bf(f.x); u.y = f2bf(f.y); u.z = f2bf(f.z); u.w = f2bf(f.w);
  *(ushort4*)&kb[(size_t)t * 256 + c4] = u;
}

// ---------------- V -> bf16 transposed vtg[d(256)][t(1024)] ----------------
__global__ __launch_bounds__(256) void vt_tr(const float* __restrict__ kvg,
                                             ushort* __restrict__ vtg) {
  __shared__ float tile[32][33];
  int t0 = blockIdx.x * 32, d0 = blockIdx.y * 32;
  int tx = threadIdx.x & 31, ty = threadIdx.x >> 5;
#pragma unroll
  for (int r = 0; r < 32; r += 8)
    tile[ty + r][tx] = kvg[(size_t)(t0 + ty + r) * KVGS + 256 + d0 + tx];
  __syncthreads();
#pragma unroll
  for (int r = 0; r < 32; r += 8)
    vtg[(size_t)(d0 + ty + r) * T_SEQ + t0 + tx] = f2bf(tile[tx][ty + r]);
}

// ---------------- block means ----------------
__global__ void cmp_mean(const float* __restrict__ kvg,
                         float* __restrict__ kc, float* __restrict__ vc) {
  int idx = blockIdx.x * blockDim.x + threadIdx.x;
  if (idx >= NBLK * NKV * DH) return;
  int d = idx & 63, hkv = (idx >> 6) & 3, n = idx >> 8;
  float sk = 0.f, sv = 0.f;
  for (int j = 0; j < BSZ; ++j) {
    size_t row = (size_t)(n * BSZ + j) * KVGS;
    sk += kvg[row + hkv * DH + d];
    sv += kvg[row + 256 + hkv * DH + d];
  }
  kc[idx] = sk * (1.0f / 64.0f);
  vc[idx] = sv * (1.0f / 64.0f);
}

__device__ __forceinline__ float wred_sum(float x) {
#pragma unroll
  for (int m = 1; m < 64; m <<= 1) x += __shfl_xor(x, m, 64);
  return x;
}

// ---------------- compressed attention + importance ----------------
__global__ __launch_bounds__(64) void cmp_attn(const float* __restrict__ q,
                                               const float* __restrict__ kc,
                                               const float* __restrict__ vc,
                                               float* __restrict__ ocmp,
                                               float* __restrict__ imp) {
  int h = blockIdx.x & 63;
  int t = blockIdx.x >> 6;
  int lane = threadIdx.x;
  int hkv = h >> 4;
  size_t qoff = ((size_t)t * NH + h) * DH + lane;
  float qd = q[qoff];
  int nv = (t >= 63) ? (((t - 63) >> 6) + 1) : 0;
  if (nv == 0) { ocmp[qoff] = 0.f; return; }
  float s[NBLK];
#pragma unroll
  for (int n = 0; n < NBLK; ++n) {
    float part = (n < nv) ? qd * kc[n * (NKV * DH) + hkv * DH + lane] : 0.f;
    part = wred_sum(part);
    s[n] = part * SCL;
  }
  float m = -INFINITY;
#pragma unroll
  for (int n = 0; n < NBLK; ++n)
    if (n < nv) m = fmaxf(m, s[n]);
  float p[NBLK];
  float denom = 0.f;
#pragma unroll
  for (int n = 0; n < NBLK; ++n) {
    p[n] = (n < nv) ? expf(s[n] - m) : 0.f;
    denom += p[n];
  }
  float rd = 1.0f / denom;
  float od = 0.f;
#pragma unroll
  for (int n = 0; n < NBLK; ++n)
    od = fmaf(p[n] * rd, vc[n * (NKV * DH) + hkv * DH + lane], od);
  ocmp[qoff] = od;
  if (lane < nv) atomicAdd(&imp[((size_t)t * NKV + hkv) * NBLK + lane], p[lane] * rd);
}

// ---------------- top-8 selection ----------------
__global__ void topk_kernel(const float* __restrict__ imp, int* __restrict__ tidx) {
  int idx = blockIdx.x * blockDim.x + threadIdx.x;
  if (idx >= T_SEQ * NKV) return;
  int t = idx >> 2;
  int cur = t >> 6;
  float vals[NBLK];
#pragma unroll
  for (int n = 0; n < NBLK; ++n) {
    float v0;
    if (n > cur) v0 = -INFINITY;
    else if (n == 0 || n == cur) v0 = INFINITY;
    else v0 = imp[(size_t)idx * NBLK + n];
    vals[n] = v0;
  }
  for (int s = 0; s < SSEL; ++s) {
    float best = -INFINITY;
    int bi = -1;
#pragma unroll
    for (int n = 0; n < NBLK; ++n) {
      if (vals[n] > best) { best = vals[n]; bi = n; }
    }
    if (bi >= 0) vals[bi] = -INFINITY;
    tidx[(size_t)idx * SSEL + s] = bi;
  }
}

// ---------------- slc+swa attention v5 ----------------
// One 256-thread block per (t,hkv). Wave w owns tiles s in {w, w+4, w+8}.
// K/V B-fragments load straight from global (L2) into registers; P A-frags
// from LDS Pb. Gates folded into Pb -> single O accumulator for both halves.
__global__ __launch_bounds__(256) void slc_swa_v5(
    const float* __restrict__ q, const float* __restrict__ kvg,
    const ushort* __restrict__ kb, const ushort* __restrict__ vtg,
    const float* __restrict__ ocmp, const int* __restrict__ tidx,
    ushort* __restrict__ obuf) {
  __shared__ __align__(16) float Sb[16 * SB_RL];   // 41.2 KB; Pb & Ored alias
  __shared__ __align__(16) ushort Qs[16 * 72];
  __shared__ int bselS[SSEL];
  ushort* Pb = (ushort*)Sb;
  float* Ored = Sb;

  int tid = threadIdx.x;
  int t = blockIdx.x >> 2, hkv = blockIdx.x & 3;
  int wv = tid >> 6, lane = tid & 63;
  int l15 = lane & 15, quad = lane >> 4;

  {
    int h = tid >> 4, d4 = (tid & 15) * 4;
    float4 f = *(const float4*)&q[(size_t)t * 4096 + (hkv * GQ + h) * 64 + d4];
    ushort4 u;
    u.x = f2bf(f.x); u.y = f2bf(f.y); u.z = f2bf(f.z); u.w = f2bf(f.w);
    *(ushort4*)&Qs[h * 72 + d4] = u;
    if (tid < SSEL) bselS[tid] = tidx[((size_t)t * NKV + hkv) * SSEL + tid];
  }
  __syncthreads();

  shortx8 qf0 = *(const shortx8*)&Qs[l15 * 72 + quad * 8];
  shortx8 qf1 = *(const shortx8*)&Qs[l15 * 72 + 32 + quad * 8];

  int lo = t - (WWIN - 1); if (lo < 0) lo = 0;
  int blo = lo >> 6, bhi = t >> 6;      // swa aligned blocks (<=9 tiles)

  floatx4 o[4];                         // 16h x 64d per wave, gate-folded
  o[0] = 0.0f; o[1] = 0.0f; o[2] = 0.0f; o[3] = 0.0f;

  for (int half = 0; half < 2; ++half) {
    // ===== scores: each wave its own tiles, no barriers inside =====
#pragma unroll
    for (int si = 0; si < 3; ++si) {
      int s = wv + si * 4;
      if (s >= NTS) continue;
      int b = -1;
      if (half == 0) { if (s < SSEL) b = bselS[s]; }
      else           { if (blo + s <= bhi) b = blo + s; }
      int pos0 = b * BSZ;
#pragma unroll
      for (int kt = 0; kt < 4; ++kt) {
        float vals[4];
        if (b >= 0) {
          int key = pos0 + kt * 16 + l15;
          const ushort* kr = &kb[(size_t)key * 256 + hkv * 64];
          shortx8 kf0 = *(const shortx8*)(kr + quad * 8);
          shortx8 kf1 = *(const shortx8*)(kr + 32 + quad * 8);
          floatx4 d = 0.0f;
          d = __builtin_amdgcn_mfma_f32_16x16x32_bf16(qf0, kf0, d, 0, 0, 0);
          d = __builtin_amdgcn_mfma_f32_16x16x32_bf16(qf1, kf1, d, 0, 0, 0);
          bool valid = (key <= t) && ((half == 0) || (key >= t - (WWIN - 1)));
#pragma unroll
          for (int r = 0; r < 4; ++r) vals[r] = valid ? d[r] * SCL : NEGF;
        } else {
#pragma unroll
          for (int r = 0; r < 4; ++r) vals[r] = NEGF;
        }
#pragma unroll
        for (int r = 0; r < 4; ++r)
          Sb[(quad * 4 + r) * SB_RL + s * 64 + kt * 16 + l15] = vals[r];
      }
    }
    __syncthreads();

    // ===== softmax over 640 cols, gate-folded bf16 probs into Pb =====
    {
      int h = tid >> 4, seg = tid & 15;
      float g = kvg[(size_t)t * KVGS + 512 + (hkv * GQ + h) * 3 + 1 + half];
      g = 1.f / (1.f + expf(-g));
      float4 r[NTS];
      float mx = -INFINITY;
#pragma unroll
      for (int c = 0; c < NTS; ++c) {
        r[c] = *(const float4*)&Sb[h * SB_RL + seg * 4 + c * 64];
        mx = fmaxf(mx, fmaxf(fmaxf(r[c].x, r[c].y), fmaxf(r[c].z, r[c].w)));
      }
#pragma unroll
      for (int m = 1; m < 16; m <<= 1) mx = fmaxf(mx, __shfl_xor(mx, m, 64));
      float sum = 0.f;
#pragma unroll
      for (int c = 0; c < NTS; ++c) {
        r[c].x = expf(r[c].x - mx); r[c].y = expf(r[c].y - mx);
        r[c].z = expf(r[c].z - mx); r[c].w = expf(r[c].w - mx);
        sum += r[c].x + r[c].y + r[c].z + r[c].w;
      }
#pragma unroll
      for (int m = 1; m < 16; m <<= 1) sum += __shfl_xor(sum, m, 64);
      float rd = g / sum;
      __syncthreads();   // fp32 Sb reads done before bf16 Pb overwrite
#pragma unroll
      for (int c = 0; c < NTS; ++c) {
        ushort4 u;
        u.x = f2bf(r[c].x * rd); u.y = f2bf(r[c].y * rd);
        u.z = f2bf(r[c].z * rd); u.w = f2bf(r[c].w * rd);
        *(ushort4*)&Pb[h * PB_RL + seg * 4 + c * 64] = u;
      }
    }
    __syncthreads();

    // ===== PV: each wave its own tiles =====
#pragma unroll
    for (int si = 0; si < 3; ++si) {
      int s = wv + si * 4;
      if (s >= NTS) continue;
      int b = -1;
      if (half == 0) { if (s < SSEL) b = bselS[s]; }
      else           { if (blo + s <= bhi) b = blo + s; }
      if (b < 0) continue;
      int pos0 = b * BSZ;
      shortx8 pf0 = *(const shortx8*)&Pb[l15 * PB_RL + s * 64 + quad * 8];
      shortx8 pf1 = *(const shortx8*)&Pb[l15 * PB_RL + s * 64 + 32 + quad * 8];
#pragma unroll
      for (int dt = 0; dt < 4; ++dt) {
        const ushort* vr = &vtg[(size_t)(hkv * 64 + dt * 16 + l15) * T_SEQ + pos0];
        shortx8 vf0 = *(const shortx8*)(vr + quad * 8);
        shortx8 vf1 = *(const shortx8*)(vr + 32 + quad * 8);
        o[dt] = __builtin_amdgcn_mfma_f32_16x16x32_bf16(pf0, vf0, o[dt], 0, 0, 0);
        o[dt] = __builtin_amdgcn_mfma_f32_16x16x32_bf16(pf1, vf1, o[dt], 0, 0, 0);
      }
    }
    __syncthreads();   // Pb reads done; next half reuses Sb
  }

  // ===== cross-wave O reduce + combine with compressed path =====
#pragma unroll
  for (int dt = 0; dt < 4; ++dt)
#pragma unroll
    for (int r = 0; r < 4; ++r)
      Ored[wv * 1024 + (quad * 4 + r) * 64 + dt * 16 + l15] = o[dt][r];
  __syncthreads();
  {
    int h = tid >> 4, d4 = (tid & 15) * 4;
    float4 sum = make_float4(0.f, 0.f, 0.f, 0.f);
#pragma unroll
    for (int w = 0; w < 4; ++w) {
      float4 p4 = *(const float4*)&Ored[w * 1024 + h * 64 + d4];
      sum.x += p4.x; sum.y += p4.y; sum.z += p4.z; sum.w += p4.w;
    }
    float g0 = kvg[(size_t)t * KVGS + 512 + (hkv * GQ + h) * 3 + 0];
    g0 = 1.f / (1.f + expf(-g0));
    size_t oo = (size_t)t * 4096 + (hkv * GQ + h) * 64 + d4;
    float4 oc = *(const float4*)&ocmp[oo];
    ushort4 u;
    u.x = f2bf(g0 * oc.x + sum.x);
    u.y = f2bf(g0 * oc.y + sum.y);
    u.z = f2bf(g0 * oc.z + sum.z);
    u.w = f2bf(g0 * oc.w + sum.w);
    *(ushort4*)&obuf[oo] = u;
  }
}

extern "C" void kernel_launch(void* const* d_in, const int* in_sizes, int n_in,
                              void* d_out, int out_size, void* d_ws, size_t ws_size,
                              hipStream_t stream) {
  const float* x  = (const float*)d_in[0];
  const float* Wq = (const float*)d_in[1];
  const float* Wk = (const float*)d_in[2];
  const float* Wv = (const float*)d_in[3];
  const float* Wg = (const float*)d_in[4];
  const float* Wo = (const float*)d_in[5];
  float* out = (float*)d_out;

  char* p = (char*)d_ws;
  ushort* xb    = (ushort*)p;  p += (size_t)1024 * 2048 * 2;
  ushort* WT    = (ushort*)p;  p += (size_t)4096 * 2048 * 2;   // WqT, later WoT
  ushort* Wkvg  = (ushort*)p;  p += (size_t)768  * 2048 * 2;
  float*  qbuf  = (float*)p;   p += (size_t)1024 * 4096 * 4;
  float*  kvg   = (float*)p;   p += (size_t)1024 * KVGS * 4;
  float*  ocmp  = (float*)p;   p += (size_t)1024 * 4096 * 4;
  ushort* obuf  = (ushort*)p;  p += (size_t)1024 * 4096 * 2;
  float*  impb  = (float*)p;   p += (size_t)65536 * 4;
  int*    tidx  = (int*)p;     p += (size_t)32768 * 4;
  float*  kc    = (float*)p;   p += (size_t)4096 * 4;
  float*  vc    = (float*)p;   p += (size_t)4096 * 4;
  ushort* kb    = (ushort*)p;  p += (size_t)1024 * 256 * 2;
  ushort* vtg   = (ushort*)p;  p += (size_t)256 * 1024 * 2;

  hipMemsetAsync(impb, 0, 65536 * sizeof(float), stream);
  hipMemsetAsync(Wkvg + (size_t)704 * 2048, 0, (size_t)64 * 2048 * 2, stream);

  cast_x<<<2048, 256, 0, stream>>>(x, xb, 1024 * 2048 / 4);
  cast_tr<<<dim3(4096 / 32, 2048 / 32), 256, 0, stream>>>(Wq, WT, 2048, 4096);
  cast_tr<<<dim3(256 / 32, 2048 / 32), 256, 0, stream>>>(Wk, Wkvg, 2048, 256);
  cast_tr<<<dim3(256 / 32, 2048 / 32), 256, 0, stream>>>(Wv, Wkvg + (size_t)256 * 2048, 2048, 256);
  cast_tr<<<dim3(192 / 32, 2048 / 32), 256, 0, stream>>>(Wg, Wkvg + (size_t)512 * 2048, 2048, 192);

  gemm_bf16_64<<<dim3(4096 / 128, 1024 / 64), 256, 0, stream>>>(xb, WT, qbuf, 1024, 4096, 2048);
  gemm_bf16_64<<<dim3(KVGS / 128, 1024 / 64), 256, 0, stream>>>(xb, Wkvg, kvg, 1024, KVGS, 2048);

  rope_f32<<<(T_SEQ * NH * 32 + 255) / 256, 256, 0, stream>>>(qbuf, NH, 4096);
  rope_f32<<<(T_SEQ * NKV * 32 + 255) / 256, 256, 0, stream>>>(kvg, NKV, KVGS);

  cast_kb<<<(T_SEQ * 256 / 4 + 255) / 256, 256, 0, stream>>>(kvg, kb);
  vt_tr<<<dim3(T_SEQ / 32, 256 / 32), 256, 0, stream>>>(kvg, vtg);

  cmp_mean<<<(NBLK * NKV * DH + 255) / 256, 256, 0, stream>>>(kvg, kc, vc);
  cmp_attn<<<T_SEQ * NH, 64, 0, stream>>>(qbuf, kc, vc, ocmp, impb);
  topk_kernel<<<(T_SEQ * NKV + 255) / 256, 256, 0, stream>>>(impb, tidx);

  slc_swa_v5<<<T_SEQ * NKV, 256, 0, stream>>>(qbuf, kvg, kb, vtg, ocmp, tidx, obuf);

  cast_tr<<<dim3(2048 / 32, 4096 / 32), 256, 0, stream>>>(Wo, WT, 4096, 2048);
  gemm_bf16_64<<<dim3(2048 / 128, 1024 / 64), 256, 0, stream>>>(obuf, WT, out, 1024, 2048, 4096);
}

// Round 8
// 409.295 us; speedup vs baseline: 7.8425x; 1.2088x over previous
//
// R7: fused cmp+topk+slc+swa (v6); bf16 q pipeline; fast-math intrinsics;
// out-GEMM 64x64 (512 blocks).
#include <hip/hip_runtime.h>
#include <hip/hip_bf16.h>
#include <math.h>

#define T_SEQ 1024
#define NH    64
#define NKV   4
#define DH    64
#define GQ    16
#define BSZ   64
#define NBLK  16
#define SSEL  8
#define WWIN  512
#define SCL   0.125f
#define NEGF  -1e30f

#define KVGS  768    // fused k|v|g row stride
#define SB_RL 644    // 640 score cols + pad (fp32)
#define PB_RL 648    // 640 prob cols + pad (bf16)
#define NTS   10

typedef float  floatx4 __attribute__((ext_vector_type(4)));
typedef short  shortx8 __attribute__((ext_vector_type(8)));

__device__ __forceinline__ ushort f2bf(float f) {
  union { float f; unsigned u; } v; v.f = f;
  unsigned r = v.u + 0x7FFF + ((v.u >> 16) & 1);
  return (ushort)(r >> 16);
}
__device__ __forceinline__ float bf2f(ushort u) {
  union { unsigned u; float f; } v; v.u = ((unsigned)u) << 16;
  return v.f;
}
__device__ __forceinline__ void gld_lds16(const ushort* g, ushort* l) {
  __builtin_amdgcn_global_load_lds((const __attribute__((address_space(1))) void*)g,
                                   (__attribute__((address_space(3))) void*)l, 16, 0, 0);
}

// ---------------- cast fp32 -> bf16 ----------------
__global__ void cast_x(const float* __restrict__ in, ushort* __restrict__ out, int n4) {
  int i = blockIdx.x * blockDim.x + threadIdx.x;
  if (i >= n4) return;
  float4 f = ((const float4*)in)[i];
  ushort4 u;
  u.x = f2bf(f.x); u.y = f2bf(f.y); u.z = f2bf(f.z); u.w = f2bf(f.w);
  ((ushort4*)out)[i] = u;
}

// ---------------- cast+transpose fp32 [K][N] -> bf16 [N][K] ----------------
__global__ __launch_bounds__(256) void cast_tr(const float* __restrict__ in,
                                               ushort* __restrict__ out, int K, int N) {
  __shared__ float tile[32][33];
  int k0 = blockIdx.y * 32, n0 = blockIdx.x * 32;
  int tx = threadIdx.x & 31, ty = threadIdx.x >> 5;
#pragma unroll
  for (int r = 0; r < 32; r += 8)
    tile[ty + r][tx] = in[(size_t)(k0 + ty + r) * N + n0 + tx];
  __syncthreads();
#pragma unroll
  for (int r = 0; r < 32; r += 8)
    out[(size_t)(n0 + ty + r) * K + k0 + tx] = f2bf(tile[tx][ty + r]);
}

// ---------------- bf16 GEMM BM64 BN128 BK64, fp32 C ----------------
__global__ __launch_bounds__(256) void gemm_bf16_64(const ushort* __restrict__ A,
                                                    const ushort* __restrict__ Bt,
                                                    float* __restrict__ C,
                                                    int M, int N, int K) {
  __shared__ ushort As[64 * 64];
  __shared__ ushort Bs[128 * 64];
  int tid = threadIdx.x, wv = tid >> 6, lane = tid & 63;
  int m0 = blockIdx.y * 64, n0 = blockIdx.x * 128;
  int l15 = lane & 15, l4 = lane >> 4;
  floatx4 acc[4][2];
#pragma unroll
  for (int i = 0; i < 4; ++i) { acc[i][0] = 0.0f; acc[i][1] = 0.0f; }
  for (int k0 = 0; k0 < K; k0 += 64) {
#pragma unroll
    for (int it = 0; it < 2; ++it) {
      int ci = (it * 4 + wv) * 64 + lane;
      gld_lds16(A + (size_t)(m0 + (ci >> 3)) * K + k0 + (ci & 7) * 8,
                As + (size_t)(it * 4 + wv) * 512);
    }
#pragma unroll
    for (int it = 0; it < 4; ++it) {
      int ci = (it * 4 + wv) * 64 + lane;
      gld_lds16(Bt + (size_t)(n0 + (ci >> 3)) * K + k0 + (ci & 7) * 8,
                Bs + (size_t)(it * 4 + wv) * 512);
    }
    __syncthreads();
#pragma unroll
    for (int ks = 0; ks < 2; ++ks) {
      shortx8 af[4], bf[2];
#pragma unroll
      for (int i = 0; i < 4; ++i)
        af[i] = *(const shortx8*)&As[(i * 16 + l15) * 64 + ks * 32 + l4 * 8];
#pragma unroll
      for (int j = 0; j < 2; ++j)
        bf[j] = *(const shortx8*)&Bs[(wv * 32 + j * 16 + l15) * 64 + ks * 32 + l4 * 8];
#pragma unroll
      for (int i = 0; i < 4; ++i)
#pragma unroll
        for (int j = 0; j < 2; ++j)
          acc[i][j] = __builtin_amdgcn_mfma_f32_16x16x32_bf16(af[i], bf[j], acc[i][j], 0, 0, 0);
    }
    __syncthreads();
  }
#pragma unroll
  for (int i = 0; i < 4; ++i)
#pragma unroll
    for (int j = 0; j < 2; ++j)
#pragma unroll
      for (int r = 0; r < 4; ++r)
        C[(size_t)(m0 + i * 16 + l4 * 4 + r) * N + n0 + wv * 32 + j * 16 + l15] = acc[i][j][r];
}

// ---------------- same but bf16 C (for q projection) ----------------
__global__ __launch_bounds__(256) void gemm_bf16_64b(const ushort* __restrict__ A,
                                                     const ushort* __restrict__ Bt,
                                                     ushort* __restrict__ C,
                                                     int M, int N, int K) {
  __shared__ ushort As[64 * 64];
  __shared__ ushort Bs[128 * 64];
  int tid = threadIdx.x, wv = tid >> 6, lane = tid & 63;
  int m0 = blockIdx.y * 64, n0 = blockIdx.x * 128;
  int l15 = lane & 15, l4 = lane >> 4;
  floatx4 acc[4][2];
#pragma unroll
  for (int i = 0; i < 4; ++i) { acc[i][0] = 0.0f; acc[i][1] = 0.0f; }
  for (int k0 = 0; k0 < K; k0 += 64) {
#pragma unroll
    for (int it = 0; it < 2; ++it) {
      int ci = (it * 4 + wv) * 64 + lane;
      gld_lds16(A + (size_t)(m0 + (ci >> 3)) * K + k0 + (ci & 7) * 8,
                As + (size_t)(it * 4 + wv) * 512);
    }
#pragma unroll
    for (int it = 0; it < 4; ++it) {
      int ci = (it * 4 + wv) * 64 + lane;
      gld_lds16(Bt + (size_t)(n0 + (ci >> 3)) * K + k0 + (ci & 7) * 8,
                Bs + (size_t)(it * 4 + wv) * 512);
    }
    __syncthreads();
#pragma unroll
    for (int ks = 0; ks < 2; ++ks) {
      shortx8 af[4], bf[2];
#pragma unroll
      for (int i = 0; i < 4; ++i)
        af[i] = *(const shortx8*)&As[(i * 16 + l15) * 64 + ks * 32 + l4 * 8];
#pragma unroll
      for (int j = 0; j < 2; ++j)
        bf[j] = *(const shortx8*)&Bs[(wv * 32 + j * 16 + l15) * 64 + ks * 32 + l4 * 8];
#pragma unroll
      for (int i = 0; i < 4; ++i)
#pragma unroll
        for (int j = 0; j < 2; ++j)
          acc[i][j] = __builtin_amdgcn_mfma_f32_16x16x32_bf16(af[i], bf[j], acc[i][j], 0, 0, 0);
    }
    __syncthreads();
  }
#pragma unroll
  for (int i = 0; i < 4; ++i)
#pragma unroll
    for (int j = 0; j < 2; ++j)
#pragma unroll
      for (int r = 0; r < 4; ++r)
        C[(size_t)(m0 + i * 16 + l4 * 4 + r) * N + n0 + wv * 32 + j * 16 + l15] =
            f2bf(acc[i][j][r]);
}

// ---------------- bf16 GEMM BM64 BN64 BK64 (out projection), fp32 C ----------------
__global__ __launch_bounds__(256) void gemm_out64(const ushort* __restrict__ A,
                                                  const ushort* __restrict__ Bt,
                                                  float* __restrict__ C,
                                                  int M, int N, int K) {
  __shared__ ushort As[64 * 64];
  __shared__ ushort Bs[64 * 64];
  int tid = threadIdx.x, wv = tid >> 6, lane = tid & 63;
  int m0 = blockIdx.y * 64, n0 = blockIdx.x * 64;
  int l15 = lane & 15, l4 = lane >> 4;
  floatx4 acc[4];
#pragma unroll
  for (int i = 0; i < 4; ++i) acc[i] = 0.0f;
  for (int k0 = 0; k0 < K; k0 += 64) {
#pragma unroll
    for (int it = 0; it < 2; ++it) {
      int ci = (it * 4 + wv) * 64 + lane;
      gld_lds16(A + (size_t)(m0 + (ci >> 3)) * K + k0 + (ci & 7) * 8,
                As + (size_t)(it * 4 + wv) * 512);
      gld_lds16(Bt + (size_t)(n0 + (ci >> 3)) * K + k0 + (ci & 7) * 8,
                Bs + (size_t)(it * 4 + wv) * 512);
    }
    __syncthreads();
#pragma unroll
    for (int ks = 0; ks < 2; ++ks) {
      shortx8 af[4], bf;
#pragma unroll
      for (int i = 0; i < 4; ++i)
        af[i] = *(const shortx8*)&As[(i * 16 + l15) * 64 + ks * 32 + l4 * 8];
      bf = *(const shortx8*)&Bs[(wv * 16 + l15) * 64 + ks * 32 + l4 * 8];
#pragma unroll
      for (int i = 0; i < 4; ++i)
        acc[i] = __builtin_amdgcn_mfma_f32_16x16x32_bf16(af[i], bf, acc[i], 0, 0, 0);
    }
    __syncthreads();
  }
#pragma unroll
  for (int i = 0; i < 4; ++i)
#pragma unroll
    for (int r = 0; r < 4; ++r)
      C[(size_t)(m0 + i * 16 + l4 * 4 + r) * N + n0 + wv * 16 + l15] = acc[i][r];
}

// ---------------- RoPE on bf16 q in place ----------------
__global__ void rope_bq(ushort* __restrict__ qb) {
  int idx = blockIdx.x * blockDim.x + threadIdx.x;
  if (idx >= T_SEQ * NH * 32) return;
  int i = idx & 31;
  int h = (idx >> 5) & 63;
  int t = idx / (32 * NH);
  float inv = __expf(-(float)i * 0.28782313662425575f);  // ln(1e4)/32
  float f = (float)t * inv;
  float s, c;
  __sincosf(f, &s, &c);
  ushort* p = qb + ((size_t)t * NH + h) * DH;
  float x1 = bf2f(p[i]), x2 = bf2f(p[i + 32]);
  p[i]      = f2bf(x1 * c - x2 * s);
  p[i + 32] = f2bf(x1 * s + x2 * c);
}

// ---------------- RoPE on fp32 kvg k-part ----------------
__global__ void rope_k(float* __restrict__ kvg) {
  int idx = blockIdx.x * blockDim.x + threadIdx.x;
  if (idx >= T_SEQ * NKV * 32) return;
  int i = idx & 31;
  int h = (idx >> 5) & 3;
  int t = idx / (32 * NKV);
  float inv = __expf(-(float)i * 0.28782313662425575f);
  float f = (float)t * inv;
  float s, c;
  __sincosf(f, &s, &c);
  float* p = kvg + (size_t)t * KVGS + h * DH;
  float x1 = p[i], x2 = p[i + 32];
  p[i]      = x1 * c - x2 * s;
  p[i + 32] = x1 * s + x2 * c;
}

// ---------------- roped K -> bf16 kb[t][256] ----------------
__global__ void cast_kb(const float* __restrict__ kvg, ushort* __restrict__ kb) {
  int i = blockIdx.x * blockDim.x + threadIdx.x;
  if (i >= T_SEQ * 256 / 4) return;
  int t = i >> 6, c4 = (i & 63) * 4;
  float4 f = *(const float4*)&kvg[(size_t)t * KVGS + c4];
  ushort4 u;
  u.x = f2bf(f.x); u.y = f2bf(f.y); u.z = f2bf(f.z); u.w = f2bf(f.w);
  *(ushort4*)&kb[(size_t)t * 256 + c4] = u;
}

// ---------------- V -> bf16 transposed vtg[d(256)][t(1024)] ----------------
__global__ __launch_bounds__(256) void vt_tr(const float* __restrict__ kvg,
                                             ushort* __restrict__ vtg) {
  __shared__ float tile[32][33];
  int t0 = blockIdx.x * 32, d0 = blockIdx.y * 32;
  int tx = threadIdx.x & 31, ty = threadIdx.x >> 5;
#pragma unroll
  for (int r = 0; r < 32; r += 8)
    tile[ty + r][tx] = kvg[(size_t)(t0 + ty + r) * KVGS + 256 + d0 + tx];
  __syncthreads();
#pragma unroll
  for (int r = 0; r < 32; r += 8)
    vtg[(size_t)(d0 + ty + r) * T_SEQ + t0 + tx] = f2bf(tile[tx][ty + r]);
}

// ---------------- block means -> bf16 kcb/vcb[n][256] ----------------
__global__ void cmp_mean(const float* __restrict__ kvg,
                         ushort* __restrict__ kcb, ushort* __restrict__ vcb) {
  int idx = blockIdx.x * blockDim.x + threadIdx.x;
  if (idx >= NBLK * NKV * DH) return;
  int d = idx & 63, hkv = (idx >> 6) & 3, n = idx >> 8;
  float sk = 0.f, sv = 0.f;
  for (int j = 0; j < BSZ; ++j) {
    size_t row = (size_t)(n * BSZ + j) * KVGS;
    sk += kvg[row + hkv * DH + d];
    sv += kvg[row + 256 + hkv * DH + d];
  }
  kcb[idx] = f2bf(sk * (1.0f / 64.0f));
  vcb[idx] = f2bf(sv * (1.0f / 64.0f));
}

// ---------------- fused cmp + topk + slc + swa (v6) ----------------
// One 256-thread block per (t,hkv). Q frags straight from global bf16 qb.
__global__ __launch_bounds__(256) void slc_swa_v6(
    const ushort* __restrict__ qb, const float* __restrict__ kvg,
    const ushort* __restrict__ kb, const ushort* __restrict__ vtg,
    const ushort* __restrict__ kcb, const ushort* __restrict__ vcb,
    ushort* __restrict__ obuf) {
  __shared__ __align__(16) float Sb[16 * SB_RL];   // Pb & Ored alias
  __shared__ __align__(16) ushort PcL[16 * 32];    // gated cmp probs (K=32 padded)
  __shared__ float impL[16];
  __shared__ int bselS[SSEL];
  ushort* Pb = (ushort*)Sb;
  float* Ored = Sb;

  int tid = threadIdx.x;
  int t = blockIdx.x >> 2, hkv = blockIdx.x & 3;
  int wv = tid >> 6, lane = tid & 63;
  int l15 = lane & 15, quad = lane >> 4;

  // Q A-fragments from global (row = head l15)
  const ushort* qrow = qb + ((size_t)t * NH + hkv * GQ + l15) * DH;
  shortx8 qf0 = *(const shortx8*)(qrow + quad * 8);
  shortx8 qf1 = *(const shortx8*)(qrow + 32 + quad * 8);

  int nv = (t >= 63) ? (((t - 63) >> 6) + 1) : 0;
  int cur = t >> 6;

  floatx4 o[4];
  o[0] = 0.0f; o[1] = 0.0f; o[2] = 0.0f; o[3] = 0.0f;

  // ===== compressed attention (all waves redundant; wv0 publishes) =====
  if (nv > 0) {
    const ushort* kcp = kcb + l15 * 256 + hkv * 64 + quad * 8;
    shortx8 kcf0 = *(const shortx8*)kcp;
    shortx8 kcf1 = *(const shortx8*)(kcp + 32);
    floatx4 dc = 0.0f;
    dc = __builtin_amdgcn_mfma_f32_16x16x32_bf16(qf0, kcf0, dc, 0, 0, 0);
    dc = __builtin_amdgcn_mfma_f32_16x16x32_bf16(qf1, kcf1, dc, 0, 0, 0);
    float s[4], p[4];
    bool cvalid = (l15 < nv);
#pragma unroll
    for (int r = 0; r < 4; ++r) s[r] = cvalid ? dc[r] * SCL : NEGF;
    float mx[4];
#pragma unroll
    for (int r = 0; r < 4; ++r) {
      float m = s[r];
#pragma unroll
      for (int msk = 1; msk < 16; msk <<= 1) m = fmaxf(m, __shfl_xor(m, msk, 64));
      mx[r] = m;
    }
    float sum[4];
#pragma unroll
    for (int r = 0; r < 4; ++r) {
      p[r] = __expf(s[r] - mx[r]);
      float su = p[r];
#pragma unroll
      for (int msk = 1; msk < 16; msk <<= 1) su += __shfl_xor(su, msk, 64);
      sum[r] = su;
    }
#pragma unroll
    for (int r = 0; r < 4; ++r) p[r] /= sum[r];
    // imp = sum over 16 heads (rows)
    float impv = p[0] + p[1] + p[2] + p[3];
    impv += __shfl_xor(impv, 16, 64);
    impv += __shfl_xor(impv, 32, 64);
    if (wv == 0) {
      if (lane < 16) impL[lane] = impv;
      // zero pad cols 16..31 of PcL
      *(uint2*)&PcL[(lane >> 2) * 32 + 16 + (lane & 3) * 4] = make_uint2(0, 0);
      // gated probs (gate g_cmp folded in)
#pragma unroll
      for (int r = 0; r < 4; ++r) {
        float g = kvg[(size_t)t * KVGS + 512 + (hkv * GQ + quad * 4 + r) * 3];
        g = 1.f / (1.f + __expf(-g));
        PcL[(quad * 4 + r) * 32 + l15] = f2bf(p[r] * g);
      }
    }
  }
  __syncthreads();

  // ===== top-8 (thread 0 serial) =====
  if (tid == 0) {
    float vals[NBLK];
#pragma unroll
    for (int n = 0; n < NBLK; ++n) {
      if (n > cur) vals[n] = -__builtin_inff();
      else if (n == 0 || n == cur) vals[n] = __builtin_inff();
      else vals[n] = impL[n];
    }
    for (int s = 0; s < SSEL; ++s) {
      float best = -__builtin_inff();
      int bi = -1;
#pragma unroll
      for (int n = 0; n < NBLK; ++n)
        if (vals[n] > best) { best = vals[n]; bi = n; }
      if (bi >= 0) vals[bi] = -__builtin_inff();
      bselS[s] = bi;
    }
  }
  __syncthreads();

  // ===== o_cmp (wv0 only): P(16x32 padded) x Vc -> D[16h][16d] per dt =====
  if (wv == 0 && nv > 0) {
    shortx8 pA = *(const shortx8*)&PcL[l15 * 32 + quad * 8];
#pragma unroll
    for (int dt = 0; dt < 4; ++dt) {
      shortx8 vB;
#pragma unroll
      for (int j = 0; j < 8; ++j)
        vB[j] = (short)vcb[((quad * 8 + j) & 15) * 256 + hkv * 64 + dt * 16 + l15];
      floatx4 oc = 0.0f;
      oc = __builtin_amdgcn_mfma_f32_16x16x32_bf16(pA, vB, oc, 0, 0, 0);
      o[dt] += oc;
    }
  }

  int lo = t - (WWIN - 1); if (lo < 0) lo = 0;
  int blo = lo >> 6, bhi = cur;

  for (int half = 0; half < 2; ++half) {
    // ----- scores -----
#pragma unroll
    for (int si = 0; si < 3; ++si) {
      int s = wv + si * 4;
      if (s >= NTS) continue;
      int b = -1;
      if (half == 0) { if (s < SSEL) b = bselS[s]; }
      else           { if (blo + s <= bhi) b = blo + s; }
      int pos0 = b * BSZ;
#pragma unroll
      for (int kt = 0; kt < 4; ++kt) {
        float vals[4];
        if (b >= 0) {
          int key = pos0 + kt * 16 + l15;
          const ushort* kr = &kb[(size_t)key * 256 + hkv * 64];
          shortx8 kf0 = *(const shortx8*)(kr + quad * 8);
          shortx8 kf1 = *(const shortx8*)(kr + 32 + quad * 8);
          floatx4 d = 0.0f;
          d = __builtin_amdgcn_mfma_f32_16x16x32_bf16(qf0, kf0, d, 0, 0, 0);
          d = __builtin_amdgcn_mfma_f32_16x16x32_bf16(qf1, kf1, d, 0, 0, 0);
          bool valid = (key <= t) && ((half == 0) || (key >= t - (WWIN - 1)));
#pragma unroll
          for (int r = 0; r < 4; ++r) vals[r] = valid ? d[r] * SCL : NEGF;
        } else {
#pragma unroll
          for (int r = 0; r < 4; ++r) vals[r] = NEGF;
        }
#pragma unroll
        for (int r = 0; r < 4; ++r)
          Sb[(quad * 4 + r) * SB_RL + s * 64 + kt * 16 + l15] = vals[r];
      }
    }
    __syncthreads();

    // ----- softmax (gate-folded) -----
    {
      int h = tid >> 4, seg = tid & 15;
      float g = kvg[(size_t)t * KVGS + 512 + (hkv * GQ + h) * 3 + 1 + half];
      g = 1.f / (1.f + __expf(-g));
      float4 r[NTS];
      float mx = -INFINITY;
#pragma unroll
      for (int c = 0; c < NTS; ++c) {
        r[c] = *(const float4*)&Sb[h * SB_RL + seg * 4 + c * 64];
        mx = fmaxf(mx, fmaxf(fmaxf(r[c].x, r[c].y), fmaxf(r[c].z, r[c].w)));
      }
#pragma unroll
      for (int m = 1; m < 16; m <<= 1) mx = fmaxf(mx, __shfl_xor(mx, m, 64));
      float sum = 0.f;
#pragma unroll
      for (int c = 0; c < NTS; ++c) {
        r[c].x = __expf(r[c].x - mx); r[c].y = __expf(r[c].y - mx);
        r[c].z = __expf(r[c].z - mx); r[c].w = __expf(r[c].w - mx);
        sum += r[c].x + r[c].y + r[c].z + r[c].w;
      }
#pragma unroll
      for (int m = 1; m < 16; m <<= 1) sum += __shfl_xor(sum, m, 64);
      float rd = g / sum;
      __syncthreads();
#pragma unroll
      for (int c = 0; c < NTS; ++c) {
        ushort4 u;
        u.x = f2bf(r[c].x * rd); u.y = f2bf(r[c].y * rd);
        u.z = f2bf(r[c].z * rd); u.w = f2bf(r[c].w * rd);
        *(ushort4*)&Pb[h * PB_RL + seg * 4 + c * 64] = u;
      }
    }
    __syncthreads();

    // ----- PV -----
#pragma unroll
    for (int si = 0; si < 3; ++si) {
      int s = wv + si * 4;
      if (s >= NTS) continue;
      int b = -1;
      if (half == 0) { if (s < SSEL) b = bselS[s]; }
      else           { if (blo + s <= bhi) b = blo + s; }
      if (b < 0) continue;
      int pos0 = b * BSZ;
      shortx8 pf0 = *(const shortx8*)&Pb[l15 * PB_RL + s * 64 + quad * 8];
      shortx8 pf1 = *(const shortx8*)&Pb[l15 * PB_RL + s * 64 + 32 + quad * 8];
#pragma unroll
      for (int dt = 0; dt < 4; ++dt) {
        const ushort* vr = &vtg[(size_t)(hkv * 64 + dt * 16 + l15) * T_SEQ + pos0];
        shortx8 vf0 = *(const shortx8*)(vr + quad * 8);
        shortx8 vf1 = *(const shortx8*)(vr + 32 + quad * 8);
        o[dt] = __builtin_amdgcn_mfma_f32_16x16x32_bf16(pf0, vf0, o[dt], 0, 0, 0);
        o[dt] = __builtin_amdgcn_mfma_f32_16x16x32_bf16(pf1, vf1, o[dt], 0, 0, 0);
      }
    }
    __syncthreads();
  }

  // ===== cross-wave O reduce + write =====
#pragma unroll
  for (int dt = 0; dt < 4; ++dt)
#pragma unroll
    for (int r = 0; r < 4; ++r)
      Ored[wv * 1024 + (quad * 4 + r) * 64 + dt * 16 + l15] = o[dt][r];
  __syncthreads();
  {
    int h = tid >> 4, d4 = (tid & 15) * 4;
    float4 sum = make_float4(0.f, 0.f, 0.f, 0.f);
#pragma unroll
    for (int w = 0; w < 4; ++w) {
      float4 p4 = *(const float4*)&Ored[w * 1024 + h * 64 + d4];
      sum.x += p4.x; sum.y += p4.y; sum.z += p4.z; sum.w += p4.w;
    }
    size_t oo = (size_t)t * 4096 + (hkv * GQ + h) * 64 + d4;
    ushort4 u;
    u.x = f2bf(sum.x); u.y = f2bf(sum.y); u.z = f2bf(sum.z); u.w = f2bf(sum.w);
    *(ushort4*)&obuf[oo] = u;
  }
}

extern "C" void kernel_launch(void* const* d_in, const int* in_sizes, int n_in,
                              void* d_out, int out_size, void* d_ws, size_t ws_size,
                              hipStream_t stream) {
  const float* x  = (const float*)d_in[0];
  const float* Wq = (const float*)d_in[1];
  const float* Wk = (const float*)d_in[2];
  const float* Wv = (const float*)d_in[3];
  const float* Wg = (const float*)d_in[4];
  const float* Wo = (const float*)d_in[5];
  float* out = (float*)d_out;

  char* p = (char*)d_ws;
  ushort* xb    = (ushort*)p;  p += (size_t)1024 * 2048 * 2;
  ushort* WT    = (ushort*)p;  p += (size_t)4096 * 2048 * 2;   // WqT, later WoT
  ushort* Wkvg  = (ushort*)p;  p += (size_t)768  * 2048 * 2;
  ushort* qbh   = (ushort*)p;  p += (size_t)1024 * 4096 * 2;   // bf16 roped q
  float*  kvg   = (float*)p;   p += (size_t)1024 * KVGS * 4;
  ushort* obuf  = (ushort*)p;  p += (size_t)1024 * 4096 * 2;
  ushort* kcb   = (ushort*)p;  p += (size_t)4096 * 2;
  ushort* vcb   = (ushort*)p;  p += (size_t)4096 * 2;
  ushort* kb    = (ushort*)p;  p += (size_t)1024 * 256 * 2;
  ushort* vtg   = (ushort*)p;  p += (size_t)256 * 1024 * 2;

  hipMemsetAsync(Wkvg + (size_t)704 * 2048, 0, (size_t)64 * 2048 * 2, stream);

  cast_x<<<2048, 256, 0, stream>>>(x, xb, 1024 * 2048 / 4);
  cast_tr<<<dim3(4096 / 32, 2048 / 32), 256, 0, stream>>>(Wq, WT, 2048, 4096);
  cast_tr<<<dim3(256 / 32, 2048 / 32), 256, 0, stream>>>(Wk, Wkvg, 2048, 256);
  cast_tr<<<dim3(256 / 32, 2048 / 32), 256, 0, stream>>>(Wv, Wkvg + (size_t)256 * 2048, 2048, 256);
  cast_tr<<<dim3(192 / 32, 2048 / 32), 256, 0, stream>>>(Wg, Wkvg + (size_t)512 * 2048, 2048, 192);

  gemm_bf16_64b<<<dim3(4096 / 128, 1024 / 64), 256, 0, stream>>>(xb, WT, qbh, 1024, 4096, 2048);
  gemm_bf16_64<<<dim3(KVGS / 128, 1024 / 64), 256, 0, stream>>>(xb, Wkvg, kvg, 1024, KVGS, 2048);

  rope_bq<<<(T_SEQ * NH * 32 + 255) / 256, 256, 0, stream>>>(qbh);
  rope_k<<<(T_SEQ * NKV * 32 + 255) / 256, 256, 0, stream>>>(kvg);

  cast_kb<<<(T_SEQ * 256 / 4 + 255) / 256, 256, 0, stream>>>(kvg, kb);
  vt_tr<<<dim3(T_SEQ / 32, 256 / 32), 256, 0, stream>>>(kvg, vtg);
  cmp_mean<<<(NBLK * NKV * DH + 255) / 256, 256, 0, stream>>>(kvg, kcb, vcb);

  slc_swa_v6<<<T_SEQ * NKV, 256, 0, stream>>>(qbh, kvg, kb, vtg, kcb, vcb, obuf);

  cast_tr<<<dim3(2048 / 32, 4096 / 32), 256, 0, stream>>>(Wo, WT, 4096, 2048);
  gemm_out64<<<dim3(2048 / 64, 1024 / 64), 256, 0, stream>>>(obuf, WT, out, 1024, 2048, 4096);
}

// Round 9
// 388.682 us; speedup vs baseline: 8.2584x; 1.0530x over previous
//
// R8: slc_swa_v7 — per-wave online softmax (flash), merge via LDS; fused
// rope_k+cast_kb; fused 3-way weight transpose. GEMMs unchanged from R7.
#include <hip/hip_runtime.h>
#include <hip/hip_bf16.h>
#include <math.h>

#define T_SEQ 1024
#define NH    64
#define NKV   4
#define DH    64
#define GQ    16
#define BSZ   64
#define NBLK  16
#define SSEL  8
#define WWIN  512
#define SCL   0.125f
#define NEGF  -1e30f
#define KVGS  768

typedef float  floatx4 __attribute__((ext_vector_type(4)));
typedef short  shortx8 __attribute__((ext_vector_type(8)));

__device__ __forceinline__ ushort f2bf(float f) {
  union { float f; unsigned u; } v; v.f = f;
  unsigned r = v.u + 0x7FFF + ((v.u >> 16) & 1);
  return (ushort)(r >> 16);
}
__device__ __forceinline__ float bf2f(ushort u) {
  union { unsigned u; float f; } v; v.u = ((unsigned)u) << 16;
  return v.f;
}
__device__ __forceinline__ void gld_lds16(const ushort* g, ushort* l) {
  __builtin_amdgcn_global_load_lds((const __attribute__((address_space(1))) void*)g,
                                   (__attribute__((address_space(3))) void*)l, 16, 0, 0);
}

// ---------------- cast fp32 -> bf16 ----------------
__global__ void cast_x(const float* __restrict__ in, ushort* __restrict__ out, int n4) {
  int i = blockIdx.x * blockDim.x + threadIdx.x;
  if (i >= n4) return;
  float4 f = ((const float4*)in)[i];
  ushort4 u;
  u.x = f2bf(f.x); u.y = f2bf(f.y); u.z = f2bf(f.z); u.w = f2bf(f.w);
  ((ushort4*)out)[i] = u;
}

// ---------------- cast+transpose fp32 [K][N] -> bf16 [N][K] ----------------
__global__ __launch_bounds__(256) void cast_tr(const float* __restrict__ in,
                                               ushort* __restrict__ out, int K, int N) {
  __shared__ float tile[32][33];
  int k0 = blockIdx.y * 32, n0 = blockIdx.x * 32;
  int tx = threadIdx.x & 31, ty = threadIdx.x >> 5;
#pragma unroll
  for (int r = 0; r < 32; r += 8)
    tile[ty + r][tx] = in[(size_t)(k0 + ty + r) * N + n0 + tx];
  __syncthreads();
#pragma unroll
  for (int r = 0; r < 32; r += 8)
    out[(size_t)(n0 + ty + r) * K + k0 + tx] = f2bf(tile[tx][ty + r]);
}

// ---------------- fused Wk|Wv|Wg cast+transpose into Wkvg[704][2048] ----------------
__global__ __launch_bounds__(256) void cast_tr_kvg(const float* __restrict__ Wk,
                                                   const float* __restrict__ Wv,
                                                   const float* __restrict__ Wg,
                                                   ushort* __restrict__ out) {
  __shared__ float tile[32][33];
  int n0 = blockIdx.x * 32;           // 0..672
  int k0 = blockIdx.y * 32;
  const float* src; int coff, Nsrc;
  if (n0 < 256)      { src = Wk; coff = n0;       Nsrc = 256; }
  else if (n0 < 512) { src = Wv; coff = n0 - 256; Nsrc = 256; }
  else               { src = Wg; coff = n0 - 512; Nsrc = 192; }
  int tx = threadIdx.x & 31, ty = threadIdx.x >> 5;
#pragma unroll
  for (int r = 0; r < 32; r += 8)
    tile[ty + r][tx] = src[(size_t)(k0 + ty + r) * Nsrc + coff + tx];
  __syncthreads();
#pragma unroll
  for (int r = 0; r < 32; r += 8)
    out[(size_t)(n0 + ty + r) * 2048 + k0 + tx] = f2bf(tile[tx][ty + r]);
}

// ---------------- bf16 GEMM BM64 BN128 BK64, fp32 C ----------------
__global__ __launch_bounds__(256) void gemm_bf16_64(const ushort* __restrict__ A,
                                                    const ushort* __restrict__ Bt,
                                                    float* __restrict__ C,
                                                    int M, int N, int K) {
  __shared__ ushort As[64 * 64];
  __shared__ ushort Bs[128 * 64];
  int tid = threadIdx.x, wv = tid >> 6, lane = tid & 63;
  int m0 = blockIdx.y * 64, n0 = blockIdx.x * 128;
  int l15 = lane & 15, l4 = lane >> 4;
  floatx4 acc[4][2];
#pragma unroll
  for (int i = 0; i < 4; ++i) { acc[i][0] = 0.0f; acc[i][1] = 0.0f; }
  for (int k0 = 0; k0 < K; k0 += 64) {
#pragma unroll
    for (int it = 0; it < 2; ++it) {
      int ci = (it * 4 + wv) * 64 + lane;
      gld_lds16(A + (size_t)(m0 + (ci >> 3)) * K + k0 + (ci & 7) * 8,
                As + (size_t)(it * 4 + wv) * 512);
    }
#pragma unroll
    for (int it = 0; it < 4; ++it) {
      int ci = (it * 4 + wv) * 64 + lane;
      gld_lds16(Bt + (size_t)(n0 + (ci >> 3)) * K + k0 + (ci & 7) * 8,
                Bs + (size_t)(it * 4 + wv) * 512);
    }
    __syncthreads();
#pragma unroll
    for (int ks = 0; ks < 2; ++ks) {
      shortx8 af[4], bf[2];
#pragma unroll
      for (int i = 0; i < 4; ++i)
        af[i] = *(const shortx8*)&As[(i * 16 + l15) * 64 + ks * 32 + l4 * 8];
#pragma unroll
      for (int j = 0; j < 2; ++j)
        bf[j] = *(const shortx8*)&Bs[(wv * 32 + j * 16 + l15) * 64 + ks * 32 + l4 * 8];
#pragma unroll
      for (int i = 0; i < 4; ++i)
#pragma unroll
        for (int j = 0; j < 2; ++j)
          acc[i][j] = __builtin_amdgcn_mfma_f32_16x16x32_bf16(af[i], bf[j], acc[i][j], 0, 0, 0);
    }
    __syncthreads();
  }
#pragma unroll
  for (int i = 0; i < 4; ++i)
#pragma unroll
    for (int j = 0; j < 2; ++j)
#pragma unroll
      for (int r = 0; r < 4; ++r)
        C[(size_t)(m0 + i * 16 + l4 * 4 + r) * N + n0 + wv * 32 + j * 16 + l15] = acc[i][j][r];
}

// ---------------- same, bf16 C (q projection) ----------------
__global__ __launch_bounds__(256) void gemm_bf16_64b(const ushort* __restrict__ A,
                                                     const ushort* __restrict__ Bt,
                                                     ushort* __restrict__ C,
                                                     int M, int N, int K) {
  __shared__ ushort As[64 * 64];
  __shared__ ushort Bs[128 * 64];
  int tid = threadIdx.x, wv = tid >> 6, lane = tid & 63;
  int m0 = blockIdx.y * 64, n0 = blockIdx.x * 128;
  int l15 = lane & 15, l4 = lane >> 4;
  floatx4 acc[4][2];
#pragma unroll
  for (int i = 0; i < 4; ++i) { acc[i][0] = 0.0f; acc[i][1] = 0.0f; }
  for (int k0 = 0; k0 < K; k0 += 64) {
#pragma unroll
    for (int it = 0; it < 2; ++it) {
      int ci = (it * 4 + wv) * 64 + lane;
      gld_lds16(A + (size_t)(m0 + (ci >> 3)) * K + k0 + (ci & 7) * 8,
                As + (size_t)(it * 4 + wv) * 512);
    }
#pragma unroll
    for (int it = 0; it < 4; ++it) {
      int ci = (it * 4 + wv) * 64 + lane;
      gld_lds16(Bt + (size_t)(n0 + (ci >> 3)) * K + k0 + (ci & 7) * 8,
                Bs + (size_t)(it * 4 + wv) * 512);
    }
    __syncthreads();
#pragma unroll
    for (int ks = 0; ks < 2; ++ks) {
      shortx8 af[4], bf[2];
#pragma unroll
      for (int i = 0; i < 4; ++i)
        af[i] = *(const shortx8*)&As[(i * 16 + l15) * 64 + ks * 32 + l4 * 8];
#pragma unroll
      for (int j = 0; j < 2; ++j)
        bf[j] = *(const shortx8*)&Bs[(wv * 32 + j * 16 + l15) * 64 + ks * 32 + l4 * 8];
#pragma unroll
      for (int i = 0; i < 4; ++i)
#pragma unroll
        for (int j = 0; j < 2; ++j)
          acc[i][j] = __builtin_amdgcn_mfma_f32_16x16x32_bf16(af[i], bf[j], acc[i][j], 0, 0, 0);
    }
    __syncthreads();
  }
#pragma unroll
  for (int i = 0; i < 4; ++i)
#pragma unroll
    for (int j = 0; j < 2; ++j)
#pragma unroll
      for (int r = 0; r < 4; ++r)
        C[(size_t)(m0 + i * 16 + l4 * 4 + r) * N + n0 + wv * 32 + j * 16 + l15] =
            f2bf(acc[i][j][r]);
}

// ---------------- bf16 GEMM BM64 BN64 (out projection), fp32 C ----------------
__global__ __launch_bounds__(256) void gemm_out64(const ushort* __restrict__ A,
                                                  const ushort* __restrict__ Bt,
                                                  float* __restrict__ C,
                                                  int M, int N, int K) {
  __shared__ ushort As[64 * 64];
  __shared__ ushort Bs[64 * 64];
  int tid = threadIdx.x, wv = tid >> 6, lane = tid & 63;
  int m0 = blockIdx.y * 64, n0 = blockIdx.x * 64;
  int l15 = lane & 15, l4 = lane >> 4;
  floatx4 acc[4];
#pragma unroll
  for (int i = 0; i < 4; ++i) acc[i] = 0.0f;
  for (int k0 = 0; k0 < K; k0 += 64) {
#pragma unroll
    for (int it = 0; it < 2; ++it) {
      int ci = (it * 4 + wv) * 64 + lane;
      gld_lds16(A + (size_t)(m0 + (ci >> 3)) * K + k0 + (ci & 7) * 8,
                As + (size_t)(it * 4 + wv) * 512);
      gld_lds16(Bt + (size_t)(n0 + (ci >> 3)) * K + k0 + (ci & 7) * 8,
                Bs + (size_t)(it * 4 + wv) * 512);
    }
    __syncthreads();
#pragma unroll
    for (int ks = 0; ks < 2; ++ks) {
      shortx8 af[4], bf;
#pragma unroll
      for (int i = 0; i < 4; ++i)
        af[i] = *(const shortx8*)&As[(i * 16 + l15) * 64 + ks * 32 + l4 * 8];
      bf = *(const shortx8*)&Bs[(wv * 16 + l15) * 64 + ks * 32 + l4 * 8];
#pragma unroll
      for (int i = 0; i < 4; ++i)
        acc[i] = __builtin_amdgcn_mfma_f32_16x16x32_bf16(af[i], bf, acc[i], 0, 0, 0);
    }
    __syncthreads();
  }
#pragma unroll
  for (int i = 0; i < 4; ++i)
#pragma unroll
    for (int r = 0; r < 4; ++r)
      C[(size_t)(m0 + i * 16 + l4 * 4 + r) * N + n0 + wv * 16 + l15] = acc[i][r];
}

// ---------------- RoPE on bf16 q ----------------
__global__ void rope_bq(ushort* __restrict__ qb) {
  int idx = blockIdx.x * blockDim.x + threadIdx.x;
  if (idx >= T_SEQ * NH * 32) return;
  int i = idx & 31;
  int h = (idx >> 5) & 63;
  int t = idx / (32 * NH);
  float inv = __expf(-(float)i * 0.28782313662425575f);
  float f = (float)t * inv;
  float s, c;
  __sincosf(f, &s, &c);
  ushort* p = qb + ((size_t)t * NH + h) * DH;
  float x1 = bf2f(p[i]), x2 = bf2f(p[i + 32]);
  p[i]      = f2bf(x1 * c - x2 * s);
  p[i + 32] = f2bf(x1 * s + x2 * c);
}

// ---------------- RoPE on fp32 k + write bf16 kb (fused) ----------------
__global__ void rope_kb(float* __restrict__ kvg, ushort* __restrict__ kb) {
  int idx = blockIdx.x * blockDim.x + threadIdx.x;
  if (idx >= T_SEQ * NKV * 32) return;
  int i = idx & 31;
  int h = (idx >> 5) & 3;
  int t = idx / (32 * NKV);
  float inv = __expf(-(float)i * 0.28782313662425575f);
  float f = (float)t * inv;
  float s, c;
  __sincosf(f, &s, &c);
  float* p = kvg + (size_t)t * KVGS + h * DH;
  float x1 = p[i], x2 = p[i + 32];
  float r1 = x1 * c - x2 * s, r2 = x1 * s + x2 * c;
  p[i] = r1; p[i + 32] = r2;
  ushort* kp = kb + (size_t)t * 256 + h * DH;
  kp[i] = f2bf(r1); kp[i + 32] = f2bf(r2);
}

// ---------------- V -> bf16 transposed vtg[d(256)][t(1024)] ----------------
__global__ __launch_bounds__(256) void vt_tr(const float* __restrict__ kvg,
                                             ushort* __restrict__ vtg) {
  __shared__ float tile[32][33];
  int t0 = blockIdx.x * 32, d0 = blockIdx.y * 32;
  int tx = threadIdx.x & 31, ty = threadIdx.x >> 5;
#pragma unroll
  for (int r = 0; r < 32; r += 8)
    tile[ty + r][tx] = kvg[(size_t)(t0 + ty + r) * KVGS + 256 + d0 + tx];
  __syncthreads();
#pragma unroll
  for (int r = 0; r < 32; r += 8)
    vtg[(size_t)(d0 + ty + r) * T_SEQ + t0 + tx] = f2bf(tile[tx][ty + r]);
}

// ---------------- block means -> bf16 kcb/vcb[n][256] ----------------
__global__ void cmp_mean(const float* __restrict__ kvg,
                         ushort* __restrict__ kcb, ushort* __restrict__ vcb) {
  int idx = blockIdx.x * blockDim.x + threadIdx.x;
  if (idx >= NBLK * NKV * DH) return;
  int d = idx & 63, hkv = (idx >> 6) & 3, n = idx >> 8;
  float sk = 0.f, sv = 0.f;
  for (int j = 0; j < BSZ; ++j) {
    size_t row = (size_t)(n * BSZ + j) * KVGS;
    sk += kvg[row + hkv * DH + d];
    sv += kvg[row + 256 + hkv * DH + d];
  }
  kcb[idx] = f2bf(sk * (1.0f / 64.0f));
  vcb[idx] = f2bf(sv * (1.0f / 64.0f));
}

// ---------------- fused cmp + topk + slc + swa, per-wave online softmax (v7) ----------------
#define OW(w, h, d) ((w) * 1064 + (h) * 66 + (d))
__global__ __launch_bounds__(256) void slc_swa_v7(
    const ushort* __restrict__ qb, const float* __restrict__ kvg,
    const ushort* __restrict__ kb, const ushort* __restrict__ vtg,
    const ushort* __restrict__ kcb, const ushort* __restrict__ vcb,
    ushort* __restrict__ obuf) {
  __shared__ __align__(16) float SMEM[4 * 1064];   // merge buffer; PtW/PcL alias
  __shared__ __align__(16) float ocmpL[16 * 66];
  __shared__ float mlm[64], mll[64], impL[16];
  __shared__ int bselS[SSEL];
  ushort* PtW = (ushort*)SMEM;                     // per-wave [16][72] bf16, pitch 1152
  ushort* PcL = (ushort*)SMEM;                     // [16][32] cmp probs (phase-ordered)

  int tid = threadIdx.x;
  int t = blockIdx.x >> 2, hkv = blockIdx.x & 3;
  int wv = tid >> 6, lane = tid & 63;
  int l15 = lane & 15, quad = lane >> 4;

  const ushort* qrow = qb + ((size_t)t * NH + hkv * GQ + l15) * DH;
  shortx8 qf0 = *(const shortx8*)(qrow + quad * 8);
  shortx8 qf1 = *(const shortx8*)(qrow + 32 + quad * 8);

  int nv = (t >= 63) ? (((t - 63) >> 6) + 1) : 0;
  int cur = t >> 6;

  // ===== compressed attention (all waves compute; wv0 publishes) =====
  if (nv > 0) {
    const ushort* kcp = kcb + l15 * 256 + hkv * 64 + quad * 8;
    shortx8 kcf0 = *(const shortx8*)kcp;
    shortx8 kcf1 = *(const shortx8*)(kcp + 32);
    floatx4 dc = 0.0f;
    dc = __builtin_amdgcn_mfma_f32_16x16x32_bf16(qf0, kcf0, dc, 0, 0, 0);
    dc = __builtin_amdgcn_mfma_f32_16x16x32_bf16(qf1, kcf1, dc, 0, 0, 0);
    float s[4], p[4];
    bool cvalid = (l15 < nv);
#pragma unroll
    for (int r = 0; r < 4; ++r) s[r] = cvalid ? dc[r] * SCL : NEGF;
#pragma unroll
    for (int r = 0; r < 4; ++r) {
      float m = s[r];
#pragma unroll
      for (int msk = 1; msk < 16; msk <<= 1) m = fmaxf(m, __shfl_xor(m, msk, 64));
      p[r] = __expf(s[r] - m);
      float su = p[r];
#pragma unroll
      for (int msk = 1; msk < 16; msk <<= 1) su += __shfl_xor(su, msk, 64);
      p[r] /= su;
    }
    float impv = p[0] + p[1] + p[2] + p[3];
    impv += __shfl_xor(impv, 16, 64);
    impv += __shfl_xor(impv, 32, 64);
    if (wv == 0) {
      if (lane < 16) impL[lane] = impv;
      *(uint2*)&PcL[(lane >> 2) * 32 + 16 + (lane & 3) * 4] = make_uint2(0, 0);
#pragma unroll
      for (int r = 0; r < 4; ++r) {
        float g = kvg[(size_t)t * KVGS + 512 + (hkv * GQ + quad * 4 + r) * 3];
        g = 1.f / (1.f + __expf(-g));
        PcL[(quad * 4 + r) * 32 + l15] = f2bf(p[r] * g);
      }
    }
  }
  __syncthreads();

  // ===== top-8 (thread 0) =====
  if (tid == 0) {
    float vals[NBLK];
#pragma unroll
    for (int n = 0; n < NBLK; ++n) {
      if (n > cur) vals[n] = -__builtin_inff();
      else if (n == 0 || n == cur) vals[n] = __builtin_inff();
      else vals[n] = impL[n];
    }
    for (int s = 0; s < SSEL; ++s) {
      float best = -__builtin_inff();
      int bi = -1;
#pragma unroll
      for (int n = 0; n < NBLK; ++n)
        if (vals[n] > best) { best = vals[n]; bi = n; }
      if (bi >= 0) vals[bi] = -__builtin_inff();
      bselS[s] = bi;
    }
  }
  // o_cmp by wv0 into ocmpL (normalized + gate-folded)
  if (wv == 0) {
    if (nv > 0) {
      shortx8 pA = *(const shortx8*)&PcL[l15 * 32 + quad * 8];
#pragma unroll
      for (int dt = 0; dt < 4; ++dt) {
        shortx8 vB;
#pragma unroll
        for (int j = 0; j < 8; ++j)
          vB[j] = (short)vcb[((quad * 8 + j) & 15) * 256 + hkv * 64 + dt * 16 + l15];
        floatx4 oc = 0.0f;
        oc = __builtin_amdgcn_mfma_f32_16x16x32_bf16(pA, vB, oc, 0, 0, 0);
#pragma unroll
        for (int r = 0; r < 4; ++r)
          ocmpL[(quad * 4 + r) * 66 + dt * 16 + l15] = oc[r];
      }
    } else {
#pragma unroll
      for (int dt = 0; dt < 4; ++dt)
#pragma unroll
        for (int r = 0; r < 4; ++r)
          ocmpL[(quad * 4 + r) * 66 + dt * 16 + l15] = 0.f;
    }
  }
  __syncthreads();   // bselS visible; PcL reads done (PtW may now be reused)

  // ===== per-wave online-softmax over owned tiles =====
  int lo = t - (WWIN - 1); if (lo < 0) lo = 0;
  int blo = lo >> 6, bhi = cur;
  int nt_swa = bhi - blo + 1;

  float m[2][4], l[2][4];
  floatx4 o[2][4];
#pragma unroll
  for (int hh = 0; hh < 2; ++hh)
#pragma unroll
    for (int r = 0; r < 4; ++r) {
      m[hh][r] = -__builtin_inff(); l[hh][r] = 0.f; o[hh][r] = 0.0f;
    }

  auto do_tile = [&](int hh, int b, bool is_swa) {
    int pos0 = b * BSZ;
    floatx4 dk[4];
#pragma unroll
    for (int kt = 0; kt < 4; ++kt) {
      int key = pos0 + kt * 16 + l15;
      const ushort* kr = &kb[(size_t)key * 256 + hkv * 64];
      shortx8 kf0 = *(const shortx8*)(kr + quad * 8);
      shortx8 kf1 = *(const shortx8*)(kr + 32 + quad * 8);
      floatx4 d = 0.0f;
      d = __builtin_amdgcn_mfma_f32_16x16x32_bf16(qf0, kf0, d, 0, 0, 0);
      d = __builtin_amdgcn_mfma_f32_16x16x32_bf16(qf1, kf1, d, 0, 0, 0);
      dk[kt] = d;
    }
#pragma unroll
    for (int kt = 0; kt < 4; ++kt) {
      int key = pos0 + kt * 16 + l15;
      bool valid = (key <= t) && (!is_swa || (key >= t - (WWIN - 1)));
#pragma unroll
      for (int r = 0; r < 4; ++r)
        dk[kt][r] = valid ? dk[kt][r] * SCL : NEGF;
    }
    float alpha[4], rs[4];
#pragma unroll
    for (int r = 0; r < 4; ++r) {
      float v = fmaxf(fmaxf(dk[0][r], dk[1][r]), fmaxf(dk[2][r], dk[3][r]));
#pragma unroll
      for (int msk = 1; msk < 16; msk <<= 1) v = fmaxf(v, __shfl_xor(v, msk, 64));
      float mn = fmaxf(m[hh][r], v);
      alpha[r] = __expf(m[hh][r] - mn);
      m[hh][r] = mn;
      rs[r] = 0.f;
    }
#pragma unroll
    for (int kt = 0; kt < 4; ++kt)
#pragma unroll
      for (int r = 0; r < 4; ++r) {
        float pv = __expf(dk[kt][r] - m[hh][r]);
        PtW[wv * 1152 + (quad * 4 + r) * 72 + kt * 16 + l15] = f2bf(pv);
        rs[r] += pv;
      }
#pragma unroll
    for (int r = 0; r < 4; ++r) {
#pragma unroll
      for (int msk = 1; msk < 16; msk <<= 1) rs[r] += __shfl_xor(rs[r], msk, 64);
      l[hh][r] = l[hh][r] * alpha[r] + rs[r];
    }
#pragma unroll
    for (int dt = 0; dt < 4; ++dt)
#pragma unroll
      for (int r = 0; r < 4; ++r)
        o[hh][dt][r] *= alpha[r];
    shortx8 pf0 = *(const shortx8*)&PtW[wv * 1152 + l15 * 72 + quad * 8];
    shortx8 pf1 = *(const shortx8*)&PtW[wv * 1152 + l15 * 72 + 32 + quad * 8];
#pragma unroll
    for (int dt = 0; dt < 4; ++dt) {
      const ushort* vr = &vtg[(size_t)(hkv * 64 + dt * 16 + l15) * T_SEQ + pos0];
      shortx8 vf0 = *(const shortx8*)(vr + quad * 8);
      shortx8 vf1 = *(const shortx8*)(vr + 32 + quad * 8);
      o[hh][dt] = __builtin_amdgcn_mfma_f32_16x16x32_bf16(pf0, vf0, o[hh][dt], 0, 0, 0);
      o[hh][dt] = __builtin_amdgcn_mfma_f32_16x16x32_bf16(pf1, vf1, o[hh][dt], 0, 0, 0);
    }
  };

#pragma unroll
  for (int si = 0; si < 2; ++si) {       // selection: tiles wv, wv+4
    int b = bselS[wv + si * 4];
    if (b >= 0) do_tile(0, b, false);
  }
#pragma unroll
  for (int si = 0; si < 3; ++si) {       // swa: tiles wv, wv+4, wv+8
    int s = wv + si * 4;
    if (s < nt_swa) do_tile(1, blo + s, true);
  }
  __syncthreads();   // all PtW use done before SMEM becomes merge buffer

  // ===== cross-wave merge (per half) + cmp + write =====
  int h = tid >> 4, d4v = (tid & 15) * 4;
  float fin[4];
#pragma unroll
  for (int j = 0; j < 4; ++j) fin[j] = ocmpL[h * 66 + d4v + j];

#pragma unroll
  for (int hh = 0; hh < 2; ++hh) {
#pragma unroll
    for (int dt = 0; dt < 4; ++dt)
#pragma unroll
      for (int r = 0; r < 4; ++r)
        SMEM[OW(wv, quad * 4 + r, dt * 16 + l15)] = o[hh][dt][r];
    if (l15 == 0) {
#pragma unroll
      for (int r = 0; r < 4; ++r) {
        mlm[wv * 16 + quad * 4 + r] = m[hh][r];
        mll[wv * 16 + quad * 4 + r] = l[hh][r];
      }
    }
    __syncthreads();
    float g = kvg[(size_t)t * KVGS + 512 + (hkv * GQ + h) * 3 + 1 + hh];
    g = 1.f / (1.f + __expf(-g));
    float M = fmaxf(fmaxf(mlm[h], mlm[16 + h]), fmaxf(mlm[32 + h], mlm[48 + h]));
    float L = 0.f, os[4] = {0.f, 0.f, 0.f, 0.f};
#pragma unroll
    for (int w = 0; w < 4; ++w) {
      float e = __expf(mlm[w * 16 + h] - M);
      L += mll[w * 16 + h] * e;
#pragma unroll
      for (int j = 0; j < 4; ++j)
        os[j] += SMEM[OW(w, h, d4v + j)] * e;
    }
    float inv = g / L;
#pragma unroll
    for (int j = 0; j < 4; ++j) fin[j] += os[j] * inv;
    __syncthreads();
  }

  size_t oo = (size_t)t * 4096 + (hkv * GQ + h) * 64 + d4v;
  ushort4 u;
  u.x = f2bf(fin[0]); u.y = f2bf(fin[1]); u.z = f2bf(fin[2]); u.w = f2bf(fin[3]);
  *(ushort4*)&obuf[oo] = u;
}

extern "C" void kernel_launch(void* const* d_in, const int* in_sizes, int n_in,
                              void* d_out, int out_size, void* d_ws, size_t ws_size,
                              hipStream_t stream) {
  const float* x  = (const float*)d_in[0];
  const float* Wq = (const float*)d_in[1];
  const float* Wk = (const float*)d_in[2];
  const float* Wv = (const float*)d_in[3];
  const float* Wg = (const float*)d_in[4];
  const float* Wo = (const float*)d_in[5];
  float* out = (float*)d_out;

  char* p = (char*)d_ws;
  ushort* xb    = (ushort*)p;  p += (size_t)1024 * 2048 * 2;
  ushort* WT    = (ushort*)p;  p += (size_t)4096 * 2048 * 2;   // WqT, later WoT
  ushort* Wkvg  = (ushort*)p;  p += (size_t)768  * 2048 * 2;
  ushort* qbh   = (ushort*)p;  p += (size_t)1024 * 4096 * 2;
  float*  kvg   = (float*)p;   p += (size_t)1024 * KVGS * 4;
  ushort* obuf  = (ushort*)p;  p += (size_t)1024 * 4096 * 2;
  ushort* kcb   = (ushort*)p;  p += (size_t)4096 * 2;
  ushort* vcb   = (ushort*)p;  p += (size_t)4096 * 2;
  ushort* kb    = (ushort*)p;  p += (size_t)1024 * 256 * 2;
  ushort* vtg   = (ushort*)p;  p += (size_t)256 * 1024 * 2;

  hipMemsetAsync(Wkvg + (size_t)704 * 2048, 0, (size_t)64 * 2048 * 2, stream);

  cast_x<<<2048, 256, 0, stream>>>(x, xb, 1024 * 2048 / 4);
  cast_tr<<<dim3(4096 / 32, 2048 / 32), 256, 0, stream>>>(Wq, WT, 2048, 4096);
  cast_tr_kvg<<<dim3(704 / 32, 2048 / 32), 256, 0, stream>>>(Wk, Wv, Wg, Wkvg);

  gemm_bf16_64b<<<dim3(4096 / 128, 1024 / 64), 256, 0, stream>>>(xb, WT, qbh, 1024, 4096, 2048);
  gemm_bf16_64<<<dim3(KVGS / 128, 1024 / 64), 256, 0, stream>>>(xb, Wkvg, kvg, 1024, KVGS, 2048);

  rope_bq<<<(T_SEQ * NH * 32 + 255) / 256, 256, 0, stream>>>(qbh);
  rope_kb<<<(T_SEQ * NKV * 32 + 255) / 256, 256, 0, stream>>>(kvg, kb);

  vt_tr<<<dim3(T_SEQ / 32, 256 / 32), 256, 0, stream>>>(kvg, vtg);
  cmp_mean<<<(NBLK * NKV * DH + 255) / 256, 256, 0, stream>>>(kvg, kcb, vcb);

  slc_swa_v7<<<T_SEQ * NKV, 256, 0, stream>>>(qbh, kvg, kb, vtg, kcb, vcb, obuf);

  cast_tr<<<dim3(2048 / 32, 4096 / 32), 256, 0, stream>>>(Wo, WT, 4096, 2048);
  gemm_out64<<<dim3(2048 / 64, 1024 / 64), 256, 0, stream>>>(obuf, WT, out, 1024, 2048, 4096);
}